// Round 12
// baseline (829.183 us; speedup 1.0000x reference)
//
#include <hip/hip_runtime.h>
#include <hip/hip_bf16.h>

// Problem constants (fixed by the reference)
#define NN 50000
#define EE 800000
#define DIN 146
#define DD 128
#define GG 64
#define LL 4
#define NC 10
#define BN_EPS 1e-5f

#define KP_EMB 160    // 146 padded to multiple of 32
#define AST_L  136    // LDS A stride (shorts) for fused gemm
#define NCOPY 64      // stat accumulator copies (contention spreading)
#define NPW 4         // nodes per wave in agg
#define SW 16         // agg column-slice width (16 cols = 32B bf16, 1.6MB/slice)
#define RST2 17       // agg LDS group stride (floats)

// mega_conv block ranges: init / repack / batch / params / wt
#define C_INIT   256
#define C_REPACK (C_INIT + 31250)
#define C_BATCH  (C_REPACK + 196)
#define C_PARAMS (C_BATCH + 384)
#define C_WT     (C_PARAMS + 400)

// edge_emb: edge conv (3125) + emb gemm (391)
#define B_EDGE 3125
#define B_TOT  (B_EDGE + 391)
// scat_mm: scatter (3125) + gemm_plain (391)
#define S_SCAT 3125
#define S_TOT  (S_SCAT + 391)

typedef __attribute__((ext_vector_type(8))) short bf16x8;
typedef __attribute__((ext_vector_type(4))) float f32x4;

__device__ __forceinline__ float bf2f(__hip_bfloat16 v) { return __bfloat162float(v); }
__device__ __forceinline__ float loadf(const void* p, long i, int f32) {
    return f32 ? ((const float*)p)[i] : bf2f(((const __hip_bfloat16*)p)[i]);
}
__device__ __forceinline__ unsigned short f2bf_bits(float f) {
    __hip_bfloat16 h = __float2bfloat16(f);
    return *(unsigned short*)&h;
}
__device__ __forceinline__ float bfu2f(unsigned short u) {
    return __uint_as_float((unsigned)u << 16);
}

// flags[0]=edge_index int64, flags[1]=batch int64, flags[2]=floats are f32
__global__ void detect_kernel(const void* ei, const void* batch, const void* Wemb,
                              int* __restrict__ flags) {
    __shared__ int s_edge_nz, s_batch_nz, s_f32_cnt;
    int t = threadIdx.x;  // 64
    if (t == 0) { s_edge_nz = 0; s_batch_nz = 0; s_f32_cnt = 0; }
    __syncthreads();
    {   const int* w = (const int*)ei;
        long j = ((long)t * ((2L * EE) / 64)) | 1;
        if (w[j] != 0) atomicAdd(&s_edge_nz, 1);
    }
    {   const int* w = (const int*)batch;
        long j = ((long)(NN / 2) + (long)t * ((NN / 2) / 64)) | 1;
        if (j < NN && w[j] != 0) atomicAdd(&s_batch_nz, 1);
    }
    {   const unsigned short* w = (const unsigned short*)Wemb;
        unsigned short v = w[2 * t];
        int ex = (v >> 7) & 0xFF;
        if (v != 0 && ex >= 128) atomicAdd(&s_f32_cnt, 1);
    }
    __syncthreads();
    if (t == 0) {
        flags[0] = (s_edge_nz == 0) ? 1 : 0;
        flags[1] = (s_batch_nz == 0) ? 1 : 0;
        flags[2] = (s_f32_cnt >= 8) ? 1 : 0;
    }
}

struct Param { const void* src; float* dst; int src_n; int dst_n; };
struct Params12 { Param p[12]; };
struct WtDesc { const void* src; long src_off; unsigned short* dst; int K; int Kpad; };
struct WtDescs5 { WtDesc p[5]; };

// merged conversions + zero-init (no atomics; all independent)
__global__ __launch_bounds__(256) void mega_conv_kernel(
    const void* __restrict__ x, const void* __restrict__ batch,
    const int* __restrict__ flags, unsigned short* __restrict__ xb,
    int* __restrict__ deg, float* __restrict__ statmulti, float* __restrict__ hgsum,
    int* __restrict__ b32, Params12 P, WtDescs5 W)
{
    int b = blockIdx.x;
    int t = threadIdx.x;
    if (b < C_INIT) {
        int i = b * 256 + t;
        if (i < NN) deg[i] = 0;
        if (i < LL * NCOPY * 256) statmulti[i] = 0.0f;
        if (i < GG * DD) hgsum[i] = 0.0f;
    } else if (b < C_REPACK) {
        int f32 = flags[2];
        long idx = (long)(b - C_INIT) * 256 + t;  // < 8,000,000 exactly
        int row = (int)(idx / KP_EMB);
        int k = (int)(idx - (long)row * KP_EMB);
        float v = (k < DIN) ? loadf(x, (long)row * DIN + k, f32) : 0.0f;
        xb[idx] = f2bf_bits(v);
    } else if (b < C_BATCH) {
        int i = (b - C_REPACK) * 256 + t;
        if (i < NN) b32[i] = flags[1] ? ((const int*)batch)[2L * i] : ((const int*)batch)[i];
    } else if (b < C_PARAMS) {
        int f32 = flags[2];
        int bb = b - C_BATCH;
        const Param& e = P.p[bb >> 5];
        int idx = (bb & 31) * 256 + t;
        if (idx < e.dst_n)
            e.dst[idx] = (idx < e.src_n) ? loadf(e.src, idx, f32) : 0.0f;
    } else {
        int f32 = flags[2];
        int bb = b - C_PARAMS;
        int y = bb / 80;
        const WtDesc& e = W.p[y];
        int idx = (bb - y * 80) * 256 + t;
        if (idx < 128 * e.Kpad) {
            int n = idx / e.Kpad, k = idx - n * e.Kpad;
            float v = (k < e.K) ? loadf(e.src, e.src_off + (long)k * DD + n, f32) : 0.0f;
            e.dst[idx] = f2bf_bits(v);
        }
    }
}

// ---- MFMA layouts ----
// A frag: m=lane&15, k=quad*8+j   B frag (from W^T): n=lane&15, k=quad*8+j
// C/D:    col=lane&15, row=quad*4+reg

// merged: edge conv+deg+rank (latency-bound atomics) || emb MFMA gemm (compute)
__global__ __launch_bounds__(256) void edge_emb_kernel(
    const void* __restrict__ ei, const int* __restrict__ flags,
    int* __restrict__ src32, int* __restrict__ dst32,
    int* __restrict__ rank, int* __restrict__ deg,
    const unsigned short* __restrict__ Ab,   // xb [n][160] bf16
    const unsigned short* __restrict__ Wt,   // [128][160] bf16 transposed
    const float* __restrict__ bias,
    float* __restrict__ h, unsigned short* __restrict__ hb, int n)
{
    int t = threadIdx.x;
    if (blockIdx.x < B_EDGE) {
        int e = blockIdx.x * 256 + t;  // < 800000 exactly
        const int* w = (const int*)ei;
        int s, d;
        if (flags[0]) { s = w[2L * e]; d = w[2L * (EE + e)]; }
        else          { s = w[e];      d = w[EE + e]; }
        src32[e] = s; dst32[e] = d;
        int r = 0;
        if ((unsigned)d < (unsigned)NN) r = atomicAdd(&deg[d], 1);
        rank[e] = r;
        return;
    }
    int r0 = (blockIdx.x - B_EDGE) * 128;
    int lane = t & 63, w = t >> 6;
    int m = lane & 15, quad = lane >> 4;
    int rbase = r0 + w * 32;
    bf16x8 a[2][5];
    #pragma unroll
    for (int rt = 0; rt < 2; ++rt)
        #pragma unroll
        for (int c = 0; c < 5; ++c) {
            int rr = rbase + rt * 16 + m; if (rr > n - 1) rr = n - 1;
            a[rt][c] = *(const bf16x8*)(Ab + (long)rr * KP_EMB + c * 32 + quad * 8);
        }
    f32x4 acc[2][8];
    #pragma unroll
    for (int t8 = 0; t8 < 8; ++t8) {
        float bv = bias[t8 * 16 + m];
        f32x4 ai = {bv, bv, bv, bv};
        acc[0][t8] = ai; acc[1][t8] = ai;
    }
    #pragma unroll
    for (int t8 = 0; t8 < 8; ++t8) {
        #pragma unroll
        for (int c = 0; c < 5; ++c) {
            bf16x8 b = *(const bf16x8*)(Wt + (long)(t8 * 16 + m) * KP_EMB + c * 32 + quad * 8);
            acc[0][t8] = __builtin_amdgcn_mfma_f32_16x16x32_bf16(a[0][c], b, acc[0][t8], 0, 0, 0);
            acc[1][t8] = __builtin_amdgcn_mfma_f32_16x16x32_bf16(a[1][c], b, acc[1][t8], 0, 0, 0);
        }
    }
    #pragma unroll
    for (int rt = 0; rt < 2; ++rt)
        #pragma unroll
        for (int t8 = 0; t8 < 8; ++t8)
            #pragma unroll
            for (int rg = 0; rg < 4; ++rg) {
                int row = rbase + rt * 16 + quad * 4 + rg;
                int col = t8 * 16 + m;
                if (row < n) {
                    float v = acc[rt][t8][rg];
                    h[(long)row * DD + col] = v;
                    hb[(long)row * DD + col] = f2bf_bits(v);
                }
            }
}

// ---- 3-phase exclusive scan (dinv fused into phase 1) ----
__global__ void scan1_kernel(const int* __restrict__ cnt, int* __restrict__ off,
                             int* __restrict__ bsum, float* __restrict__ dinv, int n) {
    int t = threadIdx.x;
    int i = blockIdx.x * 256 + t;
    int v = (i < n) ? cnt[i] : 0;
    if (i < n) dinv[i] = rsqrtf((float)(v + 1));  // +1 self-loop
    int lane = t & 63, w = t >> 6;
    int x = v;
    #pragma unroll
    for (int s = 1; s < 64; s <<= 1) {
        int y = __shfl_up(x, s, 64);
        if (lane >= s) x += y;
    }
    __shared__ int wsum[4];
    if (lane == 63) wsum[w] = x;
    __syncthreads();
    if (t == 0) {
        int a = 0;
        #pragma unroll
        for (int k = 0; k < 4; ++k) { int tmp = wsum[k]; wsum[k] = a; a += tmp; }
        bsum[blockIdx.x] = a;
    }
    __syncthreads();
    int excl = x - v + wsum[w];
    if (i < n) off[i] = excl;
}

__global__ void scan2_kernel(int* __restrict__ bsum, int* __restrict__ boff,
                             int* __restrict__ off_last, int nb) {
    int t = threadIdx.x;  // 256
    int v = (t < nb) ? bsum[t] : 0;
    int lane = t & 63, w = t >> 6;
    int x = v;
    #pragma unroll
    for (int s = 1; s < 64; s <<= 1) {
        int y = __shfl_up(x, s, 64);
        if (lane >= s) x += y;
    }
    __shared__ int wsum[4];
    if (lane == 63) wsum[w] = x;
    __syncthreads();
    __shared__ int total_s;
    if (t == 0) {
        int a = 0;
        #pragma unroll
        for (int k = 0; k < 4; ++k) { int tmp = wsum[k]; wsum[k] = a; a += tmp; }
        total_s = a;
    }
    __syncthreads();
    if (t < nb) boff[t] = x - v + wsum[w];
    if (t == 0) *off_last = total_s;
}

__global__ void scan3_kernel(int* __restrict__ off, const int* __restrict__ boff, int n) {
    int i = blockIdx.x * 256 + threadIdx.x;
    if (i < n) off[i] += boff[blockIdx.x];
}

// merged: CSR scatter (latency-bound random writes) || layer-0 gemm_plain (MFMA)
__global__ __launch_bounds__(256) void scat_mm_kernel(
    const int* __restrict__ src, const int* __restrict__ dst,
    const int* __restrict__ rank, const int* __restrict__ off,
    int* __restrict__ src_s,
    const unsigned short* __restrict__ Ab,   // hb
    const unsigned short* __restrict__ Wt,   // wt_gcn layer 0
    const float* __restrict__ dinv,
    unsigned short* __restrict__ Mb, int n)
{
    int t = threadIdx.x;
    if (blockIdx.x < S_SCAT) {
        int e = blockIdx.x * 256 + t;  // < 800000 exactly
        int s = src[e], d = dst[e];
        if ((unsigned)s >= (unsigned)NN || (unsigned)d >= (unsigned)NN) return;
        src_s[off[d] + rank[e]] = s;
        return;
    }
    int r0 = (blockIdx.x - S_SCAT) * 128;
    int lane = t & 63, w = t >> 6;
    int m = lane & 15, quad = lane >> 4;
    int rbase = r0 + w * 32;
    bf16x8 a[2][4];
    #pragma unroll
    for (int rt = 0; rt < 2; ++rt)
        #pragma unroll
        for (int c = 0; c < 4; ++c) {
            int rr = rbase + rt * 16 + m; if (rr > n - 1) rr = n - 1;
            a[rt][c] = *(const bf16x8*)(Ab + (long)rr * DD + c * 32 + quad * 8);
        }
    float dv[2][4];
    #pragma unroll
    for (int rt = 0; rt < 2; ++rt)
        #pragma unroll
        for (int rg = 0; rg < 4; ++rg) {
            int row = rbase + rt * 16 + quad * 4 + rg; if (row > n - 1) row = n - 1;
            dv[rt][rg] = dinv[row];
        }
    f32x4 acc[2][8];
    #pragma unroll
    for (int t8 = 0; t8 < 8; ++t8) {
        f32x4 z = {0.f, 0.f, 0.f, 0.f};
        acc[0][t8] = z; acc[1][t8] = z;
    }
    #pragma unroll
    for (int t8 = 0; t8 < 8; ++t8) {
        #pragma unroll
        for (int c = 0; c < 4; ++c) {
            bf16x8 b = *(const bf16x8*)(Wt + (long)(t8 * 16 + m) * DD + c * 32 + quad * 8);
            acc[0][t8] = __builtin_amdgcn_mfma_f32_16x16x32_bf16(a[0][c], b, acc[0][t8], 0, 0, 0);
            acc[1][t8] = __builtin_amdgcn_mfma_f32_16x16x32_bf16(a[1][c], b, acc[1][t8], 0, 0, 0);
        }
    }
    #pragma unroll
    for (int rt = 0; rt < 2; ++rt)
        #pragma unroll
        for (int t8 = 0; t8 < 8; ++t8)
            #pragma unroll
            for (int rg = 0; rg < 4; ++rg) {
                int row = rbase + rt * 16 + quad * 4 + rg;
                int col = t8 * 16 + m;
                if (row < n) Mb[(long)row * DD + col] = f2bf_bits(dv[rt][rg] * acc[rt][t8][rg]);
            }
}

// fused: inline stats-finalize (statmulti -> LDS) + h += relu(bn(agg)) + MFMA
__global__ __launch_bounds__(256) void gemm_fused_kernel(
    const float* __restrict__ agg, float* __restrict__ h,
    const float* __restrict__ statmulti, const float* __restrict__ gamma,
    const float* __restrict__ beta, const float* __restrict__ dinv,
    const unsigned short* __restrict__ Wt, unsigned short* __restrict__ Mb, int n)
{
    __shared__ unsigned short As[128 * AST_L];
    __shared__ float bnsh[256];
    int t = threadIdx.x;
    int r0 = blockIdx.x * 128;
    {
        float s = 0.0f;
        #pragma unroll 8
        for (int k = 0; k < NCOPY; ++k) s += statmulti[k * 256 + t];
        bnsh[t] = s;
    }
    __syncthreads();
    {
        int c4 = (t & 31) * 4, rsub = t >> 5;  // 8 row substreams
        float inv_n = 1.0f / (float)n;
        float4 sm = *(const float4*)&bnsh[c4];
        float4 sq = *(const float4*)&bnsh[128 + c4];
        float4 ga = *(const float4*)&gamma[c4];
        float4 be = *(const float4*)&beta[c4];
        float4 mu, rs;
        mu.x = sm.x * inv_n; mu.y = sm.y * inv_n; mu.z = sm.z * inv_n; mu.w = sm.w * inv_n;
        rs.x = rsqrtf(sq.x * inv_n - mu.x * mu.x + BN_EPS) * ga.x;
        rs.y = rsqrtf(sq.y * inv_n - mu.y * mu.y + BN_EPS) * ga.y;
        rs.z = rsqrtf(sq.z * inv_n - mu.z * mu.z + BN_EPS) * ga.z;
        rs.w = rsqrtf(sq.w * inv_n - mu.w * mu.w + BN_EPS) * ga.w;
        #pragma unroll 4
        for (int i = 0; i < 16; ++i) {
            int row = i * 8 + rsub;
            int r = r0 + row;
            unsigned short o0 = 0, o1 = 0, o2 = 0, o3 = 0;
            if (r < n) {
                long g = (long)r * DD + c4;
                float4 av = *(const float4*)&agg[g];
                float4 hv = *(const float4*)&h[g];
                hv.x += fmaxf((av.x - mu.x) * rs.x + be.x, 0.0f);
                hv.y += fmaxf((av.y - mu.y) * rs.y + be.y, 0.0f);
                hv.z += fmaxf((av.z - mu.z) * rs.z + be.z, 0.0f);
                hv.w += fmaxf((av.w - mu.w) * rs.w + be.w, 0.0f);
                *(float4*)&h[g] = hv;
                o0 = f2bf_bits(hv.x); o1 = f2bf_bits(hv.y);
                o2 = f2bf_bits(hv.z); o3 = f2bf_bits(hv.w);
            }
            unsigned short* dst = &As[row * AST_L + c4];
            dst[0] = o0; dst[1] = o1; dst[2] = o2; dst[3] = o3;
        }
    }
    __syncthreads();
    int lane = t & 63, w = t >> 6;
    int m = lane & 15, quad = lane >> 4;
    int rl = w * 32;
    int rbase = r0 + rl;
    bf16x8 a[2][4];
    #pragma unroll
    for (int rt = 0; rt < 2; ++rt)
        #pragma unroll
        for (int c = 0; c < 4; ++c)
            a[rt][c] = *(const bf16x8*)(As + (rl + rt * 16 + m) * AST_L + c * 32 + quad * 8);
    float dv[2][4];
    #pragma unroll
    for (int rt = 0; rt < 2; ++rt)
        #pragma unroll
        for (int rg = 0; rg < 4; ++rg) {
            int row = rbase + rt * 16 + quad * 4 + rg; if (row > n - 1) row = n - 1;
            dv[rt][rg] = dinv[row];
        }
    f32x4 acc[2][8];
    #pragma unroll
    for (int t8 = 0; t8 < 8; ++t8) {
        f32x4 z = {0.f, 0.f, 0.f, 0.f};
        acc[0][t8] = z; acc[1][t8] = z;
    }
    #pragma unroll
    for (int t8 = 0; t8 < 8; ++t8) {
        #pragma unroll
        for (int c = 0; c < 4; ++c) {
            bf16x8 b = *(const bf16x8*)(Wt + (long)(t8 * 16 + m) * DD + c * 32 + quad * 8);
            acc[0][t8] = __builtin_amdgcn_mfma_f32_16x16x32_bf16(a[0][c], b, acc[0][t8], 0, 0, 0);
            acc[1][t8] = __builtin_amdgcn_mfma_f32_16x16x32_bf16(a[1][c], b, acc[1][t8], 0, 0, 0);
        }
    }
    #pragma unroll
    for (int rt = 0; rt < 2; ++rt)
        #pragma unroll
        for (int t8 = 0; t8 < 8; ++t8)
            #pragma unroll
            for (int rg = 0; rg < 4; ++rg) {
                int row = rbase + rt * 16 + quad * 4 + rg;
                int col = t8 * 16 + m;
                if (row < n) Mb[(long)row * DD + col] = f2bf_bits(dv[rt][rg] * acc[rt][t8][rg]);
            }
}

// agg, column-sliced for XCD-L2 residency: slice = blockIdx & 7 (16 cols, 1.6MB),
// chunk = blockIdx >> 3 (16 nodes). Wave = 8 groups x 8 lanes; dword/lane fetches
// 8 edge-slices per instruction. Group-combine via per-wave LDS (stride-17,
// compile-barrier protected). Fused per-slice stats.
__global__ __launch_bounds__(256) void agg_kernel(
    const unsigned short* __restrict__ mb, const int* __restrict__ off,
    const int* __restrict__ src_s, const float* __restrict__ dinv,
    const float* __restrict__ bias, float* __restrict__ agg,
    float* __restrict__ statacc)
{
    __shared__ float sred[4][8 * RST2];
    __shared__ float sstat[4][2 * SW];
    int t = threadIdx.x;
    int wv = t >> 6, lane = t & 63;
    int grp = lane >> 3, sl = lane & 7;
    int slice = blockIdx.x & 7;
    int chunk = blockIdx.x >> 3;
    int colbase = slice * SW;
    const unsigned* M = (const unsigned*)mb;   // row = 64 uints
    long sloff = (long)slice * 8;
    float* red = sred[wv];
    float stS = 0.0f, stQ = 0.0f;
    float bi = (lane < SW) ? bias[colbase + lane] : 0.0f;
    int i0 = chunk * 16 + wv * NPW;
    #pragma unroll 1
    for (int ni = 0; ni < NPW; ++ni) {
        int i = i0 + ni;
        if (i >= NN) break;
        float a0 = 0.0f, a1 = 0.0f;
        if (grp == 0) {  // self row slice
            unsigned v = M[(long)i * 64 + sloff + sl];
            a0 += bfu2f((unsigned short)(v & 0xffff));
            a1 += bfu2f((unsigned short)(v >> 16));
        }
        int e = off[i], e1 = off[i + 1];
        for (; e + 16 <= e1; e += 16) {
            int ja = src_s[e + grp];
            int jb = src_s[e + 8 + grp];
            unsigned va = M[(long)ja * 64 + sloff + sl];
            unsigned vb = M[(long)jb * 64 + sloff + sl];
            a0 += bfu2f((unsigned short)(va & 0xffff));
            a1 += bfu2f((unsigned short)(va >> 16));
            a0 += bfu2f((unsigned short)(vb & 0xffff));
            a1 += bfu2f((unsigned short)(vb >> 16));
        }
        for (; e + 8 <= e1; e += 8) {
            int j = src_s[e + grp];
            unsigned v = M[(long)j * 64 + sloff + sl];
            a0 += bfu2f((unsigned short)(v & 0xffff));
            a1 += bfu2f((unsigned short)(v >> 16));
        }
        if (e + grp < e1) {
            int j = src_s[e + grp];
            unsigned v = M[(long)j * 64 + sloff + sl];
            a0 += bfu2f((unsigned short)(v & 0xffff));
            a1 += bfu2f((unsigned short)(v >> 16));
        }
        red[grp * RST2 + sl * 2]     = a0;
        red[grp * RST2 + sl * 2 + 1] = a1;
        asm volatile("" ::: "memory");
        if (lane < SW) {
            float c = 0.0f;
            #pragma unroll
            for (int g = 0; g < 8; ++g) c += red[g * RST2 + lane];
            float outv = dinv[i] * c + bi;
            agg[(long)i * DD + colbase + lane] = outv;
            stS += outv; stQ += outv * outv;
        }
        asm volatile("" ::: "memory");
    }
    // cross-wave per-slice stats reduce (barrier-protected), then spread atomics
    if (lane < SW) { sstat[wv][lane] = stS; sstat[wv][SW + lane] = stQ; }
    __syncthreads();
    if (wv == 0 && lane < 2 * SW) {
        float s = sstat[0][lane] + sstat[1][lane] + sstat[2][lane] + sstat[3][lane];
        float* copy = statacc + (blockIdx.x & (NCOPY - 1)) * 256;
        int c = (lane < SW) ? (colbase + lane) : (128 + colbase + (lane - SW));
        atomicAdd(&copy[c], s);
    }
}

// pooling with inline stats-finalize + fused final BN+relu+residual, float4
__global__ void pool1_kernel(const float* __restrict__ h, const float* __restrict__ agg,
                             const float* __restrict__ statmulti,
                             const float* __restrict__ gamma, const float* __restrict__ beta,
                             const int* __restrict__ b32, float* __restrict__ hgsum, int n) {
    __shared__ float bnsh[256];
    int t = threadIdx.x;
    {
        float s = 0.0f;
        #pragma unroll 8
        for (int k = 0; k < NCOPY; ++k) s += statmulti[k * 256 + t];
        bnsh[t] = s;
    }
    __syncthreads();
    int c4 = (t & 31) * 4, rsub = t >> 5;
    float inv_n = 1.0f / (float)n;
    float4 sm = *(const float4*)&bnsh[c4];
    float4 sq = *(const float4*)&bnsh[128 + c4];
    float4 ga = *(const float4*)&gamma[c4];
    float4 be = *(const float4*)&beta[c4];
    float4 mu, rs;
    mu.x = sm.x * inv_n; mu.y = sm.y * inv_n; mu.z = sm.z * inv_n; mu.w = sm.w * inv_n;
    rs.x = rsqrtf(sq.x * inv_n - mu.x * mu.x + BN_EPS) * ga.x;
    rs.y = rsqrtf(sq.y * inv_n - mu.y * mu.y + BN_EPS) * ga.y;
    rs.z = rsqrtf(sq.z * inv_n - mu.z * mu.z + BN_EPS) * ga.z;
    rs.w = rsqrtf(sq.w * inv_n - mu.w * mu.w + BN_EPS) * ga.w;
    int rows_pb = (n + gridDim.x - 1) / gridDim.x;
    int r0 = blockIdx.x * rows_pb;
    int r1 = min(n, r0 + rows_pb);
    float4 acc = {0, 0, 0, 0};
    int gcur = -1;
    for (int r = r0 + rsub; r < r1; r += 8) {
        int g = b32[r];
        if (g != gcur) {
            if (gcur >= 0) {
                atomicAdd(&hgsum[gcur * DD + c4 + 0], acc.x);
                atomicAdd(&hgsum[gcur * DD + c4 + 1], acc.y);
                atomicAdd(&hgsum[gcur * DD + c4 + 2], acc.z);
                atomicAdd(&hgsum[gcur * DD + c4 + 3], acc.w);
            }
            acc.x = acc.y = acc.z = acc.w = 0.0f;
            gcur = ((unsigned)g < (unsigned)GG) ? g : -1;
        }
        if (gcur >= 0) {
            long ix = (long)r * DD + c4;
            float4 av = *(const float4*)&agg[ix];
            float4 hv = *(const float4*)&h[ix];
            acc.x += hv.x + fmaxf((av.x - mu.x) * rs.x + be.x, 0.0f);
            acc.y += hv.y + fmaxf((av.y - mu.y) * rs.y + be.y, 0.0f);
            acc.z += hv.z + fmaxf((av.z - mu.z) * rs.z + be.z, 0.0f);
            acc.w += hv.w + fmaxf((av.w - mu.w) * rs.w + be.w, 0.0f);
        }
    }
    if (gcur >= 0) {
        atomicAdd(&hgsum[gcur * DD + c4 + 0], acc.x);
        atomicAdd(&hgsum[gcur * DD + c4 + 1], acc.y);
        atomicAdd(&hgsum[gcur * DD + c4 + 2], acc.z);
        atomicAdd(&hgsum[gcur * DD + c4 + 3], acc.w);
    }
}

__device__ int lower_bound_i(const int* __restrict__ a, int n, int v) {
    int lo = 0, hi = n;
    while (lo < hi) {
        int mid = (lo + hi) >> 1;
        if (a[mid] < v) lo = mid + 1; else hi = mid;
    }
    return lo;
}

// readout with fused mean-pool finalize
__global__ void readout_kernel(const float* __restrict__ hgsum, const int* __restrict__ b32,
                               const float* __restrict__ W1, const float* __restrict__ b1,
                               const float* __restrict__ W2, const float* __restrict__ b2,
                               const float* __restrict__ W3, const float* __restrict__ b3,
                               const int* __restrict__ flags, void* __restrict__ out, int n) {
    int f32 = flags[2];
    int g = blockIdx.x;
    int t = threadIdx.x;
    __shared__ float hgs[DD];
    __shared__ float z1[DD / 2];
    __shared__ float z2[DD / 4];
    int lo = lower_bound_i(b32, n, g);
    int hi = lower_bound_i(b32, n, g + 1);
    float invc = 1.0f / fmaxf((float)(hi - lo), 1.0f);
    hgs[t] = hgsum[g * DD + t] * invc;
    __syncthreads();
    if (t < DD / 2) {
        float acc = b1[t];
        #pragma unroll 8
        for (int k = 0; k < DD; ++k) acc = fmaf(hgs[k], W1[k * (DD / 2) + t], acc);
        z1[t] = fmaxf(acc, 0.0f);
    }
    __syncthreads();
    if (t < DD / 4) {
        float acc = b2[t];
        #pragma unroll 8
        for (int k = 0; k < DD / 2; ++k) acc = fmaf(z1[k], W2[k * (DD / 4) + t], acc);
        z2[t] = fmaxf(acc, 0.0f);
    }
    __syncthreads();
    if (t < NC) {
        float acc = b3[t];
        #pragma unroll 8
        for (int k = 0; k < DD / 4; ++k) acc = fmaf(z2[k], W3[k * NC + t], acc);
        if (f32) ((float*)out)[g * NC + t] = acc;
        else     ((__hip_bfloat16*)out)[g * NC + t] = __float2bfloat16(acc);
    }
}

extern "C" void kernel_launch(void* const* d_in, const int* in_sizes, int n_in,
                              void* d_out, int out_size, void* d_ws, size_t ws_size,
                              hipStream_t stream) {
    const void* x      = d_in[0];
    const void* ei     = d_in[1];
    const void* batch  = d_in[2];
    const void* W_emb  = d_in[3];
    const void* b_emb  = d_in[4];
    const void* W_gcn  = d_in[5];
    const void* b_gcn  = d_in[6];
    const void* bn_g   = d_in[7];
    const void* bn_b   = d_in[8];
    const void* W_r1   = d_in[9];
    const void* b_r1   = d_in[10];
    const void* W_r2   = d_in[11];
    const void* b_r2   = d_in[12];
    const void* W_r3   = d_in[13];
    const void* b_r3   = d_in[14];

    char* p = (char*)d_ws;
    auto alloc = [&](size_t bytes) -> void* {
        void* r = (void*)p;
        p += (bytes + 255) & ~(size_t)255;
        return r;
    };
    int*   flags  = (int*)alloc(64 * 4);
    int*   deg    = (int*)alloc((size_t)NN * 4);
    float* statmulti = (float*)alloc((size_t)LL * NCOPY * 256 * 4);
    float* hgsum  = (float*)alloc((size_t)GG * DD * 4);
    int*   off    = (int*)alloc((size_t)(NN + 1) * 4);
    float* dinv   = (float*)alloc((size_t)NN * 4);
    int*   src32  = (int*)alloc((size_t)EE * 4);
    int*   dst32  = (int*)alloc((size_t)EE * 4);
    int*   rank   = (int*)alloc((size_t)EE * 4);
    int*   b32    = (int*)alloc((size_t)NN * 4);
    int*   src_s  = (int*)alloc((size_t)EE * 4);
    int*   bsum   = (int*)alloc(256 * 4);
    int*   boff   = (int*)alloc(256 * 4);
    float* h      = (float*)alloc((size_t)NN * DD * 4);
    unsigned short* hb = (unsigned short*)alloc((size_t)NN * DD * 2);
    unsigned short* mb = (unsigned short*)alloc((size_t)NN * DD * 2);
    float* agg    = (float*)alloc((size_t)NN * DD * 4);
    // xb aliases agg: xb (16MB bf16) only live before first agg write
    unsigned short* xb = (unsigned short*)agg;
    // canonical params
    unsigned short* wt_emb = (unsigned short*)alloc((size_t)DD * KP_EMB * 2);
    unsigned short* wt_gcn = (unsigned short*)alloc((size_t)LL * DD * DD * 2);
    float* b_emb32 = (float*)alloc(DD * 4);
    float* b_gcn32 = (float*)alloc((size_t)LL * DD * 4);
    float* bng32   = (float*)alloc((size_t)LL * DD * 4);
    float* bnb32   = (float*)alloc((size_t)LL * DD * 4);
    float* wr1     = (float*)alloc((size_t)DD * (DD / 2) * 4);
    float* br1     = (float*)alloc((DD / 2) * 4);
    float* wr2     = (float*)alloc((size_t)(DD / 2) * (DD / 4) * 4);
    float* br2     = (float*)alloc((DD / 4) * 4);
    float* wr3     = (float*)alloc((size_t)(DD / 4) * NC * 4);
    float* br3     = (float*)alloc(NC * 4);

    detect_kernel<<<1, 64, 0, stream>>>(ei, batch, W_emb, flags);

    Params12 P;
    P.p[0]  = { b_emb, b_emb32, DD, DD };
    P.p[1]  = { b_gcn, b_gcn32, LL * DD, LL * DD };
    P.p[2]  = { bn_g,  bng32,   LL * DD, LL * DD };
    P.p[3]  = { bn_b,  bnb32,   LL * DD, LL * DD };
    P.p[4]  = { W_r1,  wr1,     DD * (DD / 2), DD * (DD / 2) };
    P.p[5]  = { b_r1,  br1,     DD / 2, DD / 2 };
    P.p[6]  = { W_r2,  wr2,     (DD / 2) * (DD / 4), (DD / 2) * (DD / 4) };
    P.p[7]  = { b_r2,  br2,     DD / 4, DD / 4 };
    P.p[8]  = { W_r3,  wr3,     (DD / 4) * NC, (DD / 4) * NC };
    P.p[9]  = { b_r3,  br3,     NC, NC };
    P.p[10] = { b_r3,  br3,     0, 0 };
    P.p[11] = { b_r3,  br3,     0, 0 };

    WtDescs5 W;
    W.p[0] = { W_emb, 0,            wt_emb,                DIN, KP_EMB };
    W.p[1] = { W_gcn, 0L * DD * DD, wt_gcn + 0L * DD * DD, DD,  DD };
    W.p[2] = { W_gcn, 1L * DD * DD, wt_gcn + 1L * DD * DD, DD,  DD };
    W.p[3] = { W_gcn, 2L * DD * DD, wt_gcn + 2L * DD * DD, DD,  DD };
    W.p[4] = { W_gcn, 3L * DD * DD, wt_gcn + 3L * DD * DD, DD,  DD };

    mega_conv_kernel<<<C_WT, 256, 0, stream>>>(x, batch, flags, xb, deg, statmulti,
                                               hgsum, b32, P, W);

    edge_emb_kernel<<<B_TOT, 256, 0, stream>>>(ei, flags, src32, dst32, rank, deg,
                                               xb, wt_emb, b_emb32, h, hb, NN);

    int nb = (NN + 255) / 256;  // 196
    scan1_kernel<<<nb, 256, 0, stream>>>(deg, off, bsum, dinv, NN);
    scan2_kernel<<<1, 256, 0, stream>>>(bsum, boff, off + NN, nb);
    scan3_kernel<<<nb, 256, 0, stream>>>(off, boff, NN);

    scat_mm_kernel<<<S_TOT, 256, 0, stream>>>(src32, dst32, rank, off, src_s,
                                              hb, wt_gcn, dinv, mb, NN);

    int ngemm = (NN + 127) / 128;  // 391
    int nagg = ((NN + 15) / 16) * 8;  // 3125 chunks x 8 slices = 25000 blocks
    for (int l = 0; l < LL; ++l) {
        if (l > 0) {
            gemm_fused_kernel<<<ngemm, 256, 0, stream>>>(
                agg, h, statmulti + (size_t)(l - 1) * NCOPY * 256,
                bng32 + (l - 1) * DD, bnb32 + (l - 1) * DD,
                dinv, wt_gcn + (size_t)l * DD * DD, mb, NN);
        }
        agg_kernel<<<nagg, 256, 0, stream>>>(mb, off, src_s, dinv,
                                             b_gcn32 + l * DD, agg,
                                             statmulti + (size_t)l * NCOPY * 256);
    }

    pool1_kernel<<<512, 256, 0, stream>>>(h, agg, statmulti + (size_t)(LL - 1) * NCOPY * 256,
                                          bng32 + (LL - 1) * DD, bnb32 + (LL - 1) * DD,
                                          b32, hgsum, NN);
    readout_kernel<<<GG, DD, 0, stream>>>(hgsum, b32, wr1, br1, wr2, br2, wr3, br3,
                                          flags, d_out, NN);
}

// Round 13
// 453.265 us; speedup vs baseline: 1.8294x; 1.8294x over previous
//
#include <hip/hip_runtime.h>
#include <hip/hip_bf16.h>

// Problem constants (fixed by the reference)
#define NN 50000
#define EE 800000
#define DIN 146
#define DD 128
#define GG 64
#define LL 4
#define NC 10
#define BN_EPS 1e-5f

#define KP_EMB 160    // 146 padded to multiple of 32
#define AST_L  136    // LDS A stride (shorts) for fused gemm
#define NCOPY 64      // stat accumulator copies (contention spreading)
#define NPW 4         // nodes per wave in agg
#define RST 129       // agg LDS group stride (floats)

// mega_conv block ranges: init / repack / batch / params / wt
#define C_INIT   256
#define C_REPACK (C_INIT + 31250)
#define C_BATCH  (C_REPACK + 196)
#define C_PARAMS (C_BATCH + 384)
#define C_WT     (C_PARAMS + 400)

// edge_emb: edge conv (3125) + emb gemm (391)
#define B_EDGE 3125
#define B_TOT  (B_EDGE + 391)
// scat_mm: scatter (3125) + gemm_plain (391)
#define S_SCAT 3125
#define S_TOT  (S_SCAT + 391)

typedef __attribute__((ext_vector_type(8))) short bf16x8;
typedef __attribute__((ext_vector_type(4))) float f32x4;

__device__ __forceinline__ float bf2f(__hip_bfloat16 v) { return __bfloat162float(v); }
__device__ __forceinline__ float loadf(const void* p, long i, int f32) {
    return f32 ? ((const float*)p)[i] : bf2f(((const __hip_bfloat16*)p)[i]);
}
__device__ __forceinline__ unsigned short f2bf_bits(float f) {
    __hip_bfloat16 h = __float2bfloat16(f);
    return *(unsigned short*)&h;
}
__device__ __forceinline__ float bfu2f(unsigned short u) {
    return __uint_as_float((unsigned)u << 16);
}
__device__ __forceinline__ void acc_add8(float* acc, uint4 v) {
    acc[0] += __uint_as_float(v.x << 16);
    acc[1] += __uint_as_float(v.x & 0xffff0000u);
    acc[2] += __uint_as_float(v.y << 16);
    acc[3] += __uint_as_float(v.y & 0xffff0000u);
    acc[4] += __uint_as_float(v.z << 16);
    acc[5] += __uint_as_float(v.z & 0xffff0000u);
    acc[6] += __uint_as_float(v.w << 16);
    acc[7] += __uint_as_float(v.w & 0xffff0000u);
}

// flags[0]=edge_index int64, flags[1]=batch int64, flags[2]=floats are f32
__global__ void detect_kernel(const void* ei, const void* batch, const void* Wemb,
                              int* __restrict__ flags) {
    __shared__ int s_edge_nz, s_batch_nz, s_f32_cnt;
    int t = threadIdx.x;  // 64
    if (t == 0) { s_edge_nz = 0; s_batch_nz = 0; s_f32_cnt = 0; }
    __syncthreads();
    {   const int* w = (const int*)ei;
        long j = ((long)t * ((2L * EE) / 64)) | 1;
        if (w[j] != 0) atomicAdd(&s_edge_nz, 1);
    }
    {   const int* w = (const int*)batch;
        long j = ((long)(NN / 2) + (long)t * ((NN / 2) / 64)) | 1;
        if (j < NN && w[j] != 0) atomicAdd(&s_batch_nz, 1);
    }
    {   const unsigned short* w = (const unsigned short*)Wemb;
        unsigned short v = w[2 * t];
        int ex = (v >> 7) & 0xFF;
        if (v != 0 && ex >= 128) atomicAdd(&s_f32_cnt, 1);
    }
    __syncthreads();
    if (t == 0) {
        flags[0] = (s_edge_nz == 0) ? 1 : 0;
        flags[1] = (s_batch_nz == 0) ? 1 : 0;
        flags[2] = (s_f32_cnt >= 8) ? 1 : 0;
    }
}

struct Param { const void* src; float* dst; int src_n; int dst_n; };
struct Params12 { Param p[12]; };
struct WtDesc { const void* src; long src_off; unsigned short* dst; int K; int Kpad; };
struct WtDescs5 { WtDesc p[5]; };

// merged conversions + zero-init (no atomics; all independent)
__global__ __launch_bounds__(256) void mega_conv_kernel(
    const void* __restrict__ x, const void* __restrict__ batch,
    const int* __restrict__ flags, unsigned short* __restrict__ xb,
    int* __restrict__ deg, float* __restrict__ statmulti, float* __restrict__ hgsum,
    int* __restrict__ b32, Params12 P, WtDescs5 W)
{
    int b = blockIdx.x;
    int t = threadIdx.x;
    if (b < C_INIT) {
        int i = b * 256 + t;
        if (i < NN) deg[i] = 0;
        if (i < LL * NCOPY * 256) statmulti[i] = 0.0f;
        if (i < GG * DD) hgsum[i] = 0.0f;
    } else if (b < C_REPACK) {
        int f32 = flags[2];
        long idx = (long)(b - C_INIT) * 256 + t;  // < 8,000,000 exactly
        int row = (int)(idx / KP_EMB);
        int k = (int)(idx - (long)row * KP_EMB);
        float v = (k < DIN) ? loadf(x, (long)row * DIN + k, f32) : 0.0f;
        xb[idx] = f2bf_bits(v);
    } else if (b < C_BATCH) {
        int i = (b - C_REPACK) * 256 + t;
        if (i < NN) b32[i] = flags[1] ? ((const int*)batch)[2L * i] : ((const int*)batch)[i];
    } else if (b < C_PARAMS) {
        int f32 = flags[2];
        int bb = b - C_BATCH;
        const Param& e = P.p[bb >> 5];
        int idx = (bb & 31) * 256 + t;
        if (idx < e.dst_n)
            e.dst[idx] = (idx < e.src_n) ? loadf(e.src, idx, f32) : 0.0f;
    } else {
        int f32 = flags[2];
        int bb = b - C_PARAMS;
        int y = bb / 80;
        const WtDesc& e = W.p[y];
        int idx = (bb - y * 80) * 256 + t;
        if (idx < 128 * e.Kpad) {
            int n = idx / e.Kpad, k = idx - n * e.Kpad;
            float v = (k < e.K) ? loadf(e.src, e.src_off + (long)k * DD + n, f32) : 0.0f;
            e.dst[idx] = f2bf_bits(v);
        }
    }
}

// ---- MFMA layouts ----
// A frag: m=lane&15, k=quad*8+j   B frag (from W^T): n=lane&15, k=quad*8+j
// C/D:    col=lane&15, row=quad*4+reg

// merged: edge conv+deg+rank (latency-bound atomics) || emb MFMA gemm.
// h is stored bf16-only (hb).
__global__ __launch_bounds__(256) void edge_emb_kernel(
    const void* __restrict__ ei, const int* __restrict__ flags,
    int* __restrict__ src32, int* __restrict__ dst32,
    int* __restrict__ rank, int* __restrict__ deg,
    const unsigned short* __restrict__ Ab,   // xb [n][160] bf16
    const unsigned short* __restrict__ Wt,   // [128][160] bf16 transposed
    const float* __restrict__ bias,
    unsigned short* __restrict__ hb, int n)
{
    int t = threadIdx.x;
    if (blockIdx.x < B_EDGE) {
        int e = blockIdx.x * 256 + t;  // < 800000 exactly
        const int* w = (const int*)ei;
        int s, d;
        if (flags[0]) { s = w[2L * e]; d = w[2L * (EE + e)]; }
        else          { s = w[e];      d = w[EE + e]; }
        src32[e] = s; dst32[e] = d;
        int r = 0;
        if ((unsigned)d < (unsigned)NN) r = atomicAdd(&deg[d], 1);
        rank[e] = r;
        return;
    }
    int r0 = (blockIdx.x - B_EDGE) * 128;
    int lane = t & 63, w = t >> 6;
    int m = lane & 15, quad = lane >> 4;
    int rbase = r0 + w * 32;
    bf16x8 a[2][5];
    #pragma unroll
    for (int rt = 0; rt < 2; ++rt)
        #pragma unroll
        for (int c = 0; c < 5; ++c) {
            int rr = rbase + rt * 16 + m; if (rr > n - 1) rr = n - 1;
            a[rt][c] = *(const bf16x8*)(Ab + (long)rr * KP_EMB + c * 32 + quad * 8);
        }
    f32x4 acc[2][8];
    #pragma unroll
    for (int t8 = 0; t8 < 8; ++t8) {
        float bv = bias[t8 * 16 + m];
        f32x4 ai = {bv, bv, bv, bv};
        acc[0][t8] = ai; acc[1][t8] = ai;
    }
    #pragma unroll
    for (int t8 = 0; t8 < 8; ++t8) {
        #pragma unroll
        for (int c = 0; c < 5; ++c) {
            bf16x8 b = *(const bf16x8*)(Wt + (long)(t8 * 16 + m) * KP_EMB + c * 32 + quad * 8);
            acc[0][t8] = __builtin_amdgcn_mfma_f32_16x16x32_bf16(a[0][c], b, acc[0][t8], 0, 0, 0);
            acc[1][t8] = __builtin_amdgcn_mfma_f32_16x16x32_bf16(a[1][c], b, acc[1][t8], 0, 0, 0);
        }
    }
    #pragma unroll
    for (int rt = 0; rt < 2; ++rt)
        #pragma unroll
        for (int t8 = 0; t8 < 8; ++t8)
            #pragma unroll
            for (int rg = 0; rg < 4; ++rg) {
                int row = rbase + rt * 16 + quad * 4 + rg;
                int col = t8 * 16 + m;
                if (row < n) hb[(long)row * DD + col] = f2bf_bits(acc[rt][t8][rg]);
            }
}

// ---- 3-phase exclusive scan (dinv fused into phase 1) ----
__global__ void scan1_kernel(const int* __restrict__ cnt, int* __restrict__ off,
                             int* __restrict__ bsum, float* __restrict__ dinv, int n) {
    int t = threadIdx.x;
    int i = blockIdx.x * 256 + t;
    int v = (i < n) ? cnt[i] : 0;
    if (i < n) dinv[i] = rsqrtf((float)(v + 1));  // +1 self-loop
    int lane = t & 63, w = t >> 6;
    int x = v;
    #pragma unroll
    for (int s = 1; s < 64; s <<= 1) {
        int y = __shfl_up(x, s, 64);
        if (lane >= s) x += y;
    }
    __shared__ int wsum[4];
    if (lane == 63) wsum[w] = x;
    __syncthreads();
    if (t == 0) {
        int a = 0;
        #pragma unroll
        for (int k = 0; k < 4; ++k) { int tmp = wsum[k]; wsum[k] = a; a += tmp; }
        bsum[blockIdx.x] = a;
    }
    __syncthreads();
    int excl = x - v + wsum[w];
    if (i < n) off[i] = excl;
}

__global__ void scan2_kernel(int* __restrict__ bsum, int* __restrict__ boff,
                             int* __restrict__ off_last, int nb) {
    int t = threadIdx.x;  // 256
    int v = (t < nb) ? bsum[t] : 0;
    int lane = t & 63, w = t >> 6;
    int x = v;
    #pragma unroll
    for (int s = 1; s < 64; s <<= 1) {
        int y = __shfl_up(x, s, 64);
        if (lane >= s) x += y;
    }
    __shared__ int wsum[4];
    if (lane == 63) wsum[w] = x;
    __syncthreads();
    __shared__ int total_s;
    if (t == 0) {
        int a = 0;
        #pragma unroll
        for (int k = 0; k < 4; ++k) { int tmp = wsum[k]; wsum[k] = a; a += tmp; }
        total_s = a;
    }
    __syncthreads();
    if (t < nb) boff[t] = x - v + wsum[w];
    if (t == 0) *off_last = total_s;
}

__global__ void scan3_kernel(int* __restrict__ off, const int* __restrict__ boff, int n) {
    int i = blockIdx.x * 256 + threadIdx.x;
    if (i < n) off[i] += boff[blockIdx.x];
}

// merged: CSR scatter (latency-bound random writes) || layer-0 gemm_plain (MFMA)
__global__ __launch_bounds__(256) void scat_mm_kernel(
    const int* __restrict__ src, const int* __restrict__ dst,
    const int* __restrict__ rank, const int* __restrict__ off,
    int* __restrict__ src_s,
    const unsigned short* __restrict__ Ab,   // hb
    const unsigned short* __restrict__ Wt,   // wt_gcn layer 0
    const float* __restrict__ dinv,
    unsigned short* __restrict__ Mb, int n)
{
    int t = threadIdx.x;
    if (blockIdx.x < S_SCAT) {
        int e = blockIdx.x * 256 + t;  // < 800000 exactly
        int s = src[e], d = dst[e];
        if ((unsigned)s >= (unsigned)NN || (unsigned)d >= (unsigned)NN) return;
        src_s[off[d] + rank[e]] = s;
        return;
    }
    int r0 = (blockIdx.x - S_SCAT) * 128;
    int lane = t & 63, w = t >> 6;
    int m = lane & 15, quad = lane >> 4;
    int rbase = r0 + w * 32;
    bf16x8 a[2][4];
    #pragma unroll
    for (int rt = 0; rt < 2; ++rt)
        #pragma unroll
        for (int c = 0; c < 4; ++c) {
            int rr = rbase + rt * 16 + m; if (rr > n - 1) rr = n - 1;
            a[rt][c] = *(const bf16x8*)(Ab + (long)rr * DD + c * 32 + quad * 8);
        }
    float dv[2][4];
    #pragma unroll
    for (int rt = 0; rt < 2; ++rt)
        #pragma unroll
        for (int rg = 0; rg < 4; ++rg) {
            int row = rbase + rt * 16 + quad * 4 + rg; if (row > n - 1) row = n - 1;
            dv[rt][rg] = dinv[row];
        }
    f32x4 acc[2][8];
    #pragma unroll
    for (int t8 = 0; t8 < 8; ++t8) {
        f32x4 z = {0.f, 0.f, 0.f, 0.f};
        acc[0][t8] = z; acc[1][t8] = z;
    }
    #pragma unroll
    for (int t8 = 0; t8 < 8; ++t8) {
        #pragma unroll
        for (int c = 0; c < 4; ++c) {
            bf16x8 b = *(const bf16x8*)(Wt + (long)(t8 * 16 + m) * DD + c * 32 + quad * 8);
            acc[0][t8] = __builtin_amdgcn_mfma_f32_16x16x32_bf16(a[0][c], b, acc[0][t8], 0, 0, 0);
            acc[1][t8] = __builtin_amdgcn_mfma_f32_16x16x32_bf16(a[1][c], b, acc[1][t8], 0, 0, 0);
        }
    }
    #pragma unroll
    for (int rt = 0; rt < 2; ++rt)
        #pragma unroll
        for (int t8 = 0; t8 < 8; ++t8)
            #pragma unroll
            for (int rg = 0; rg < 4; ++rg) {
                int row = rbase + rt * 16 + quad * 4 + rg;
                int col = t8 * 16 + m;
                if (row < n) Mb[(long)row * DD + col] = f2bf_bits(dv[rt][rg] * acc[rt][t8][rg]);
            }
}

// fused: inline stats-finalize + hb += relu(bn(agg)) (bf16 in-place) + MFMA
__global__ __launch_bounds__(256) void gemm_fused_kernel(
    const float* __restrict__ agg, unsigned short* __restrict__ hb,
    const float* __restrict__ statmulti, const float* __restrict__ gamma,
    const float* __restrict__ beta, const float* __restrict__ dinv,
    const unsigned short* __restrict__ Wt, unsigned short* __restrict__ Mb, int n)
{
    __shared__ unsigned short As[128 * AST_L];
    __shared__ float bnsh[256];
    int t = threadIdx.x;
    int r0 = blockIdx.x * 128;
    {
        float s = 0.0f;
        #pragma unroll 8
        for (int k = 0; k < NCOPY; ++k) s += statmulti[k * 256 + t];
        bnsh[t] = s;
    }
    __syncthreads();
    {
        int c4 = (t & 31) * 4, rsub = t >> 5;  // 8 row substreams
        float inv_n = 1.0f / (float)n;
        float4 sm = *(const float4*)&bnsh[c4];
        float4 sq = *(const float4*)&bnsh[128 + c4];
        float4 ga = *(const float4*)&gamma[c4];
        float4 be = *(const float4*)&beta[c4];
        float4 mu, rs;
        mu.x = sm.x * inv_n; mu.y = sm.y * inv_n; mu.z = sm.z * inv_n; mu.w = sm.w * inv_n;
        rs.x = rsqrtf(sq.x * inv_n - mu.x * mu.x + BN_EPS) * ga.x;
        rs.y = rsqrtf(sq.y * inv_n - mu.y * mu.y + BN_EPS) * ga.y;
        rs.z = rsqrtf(sq.z * inv_n - mu.z * mu.z + BN_EPS) * ga.z;
        rs.w = rsqrtf(sq.w * inv_n - mu.w * mu.w + BN_EPS) * ga.w;
        #pragma unroll 4
        for (int i = 0; i < 16; ++i) {
            int row = i * 8 + rsub;
            int r = r0 + row;
            unsigned short o0 = 0, o1 = 0, o2 = 0, o3 = 0;
            if (r < n) {
                long g = (long)r * DD + c4;
                float4 av = *(const float4*)&agg[g];
                ushort4 hu = *(const ushort4*)&hb[g];
                float h0 = bfu2f(hu.x) + fmaxf((av.x - mu.x) * rs.x + be.x, 0.0f);
                float h1 = bfu2f(hu.y) + fmaxf((av.y - mu.y) * rs.y + be.y, 0.0f);
                float h2 = bfu2f(hu.z) + fmaxf((av.z - mu.z) * rs.z + be.z, 0.0f);
                float h3 = bfu2f(hu.w) + fmaxf((av.w - mu.w) * rs.w + be.w, 0.0f);
                o0 = f2bf_bits(h0); o1 = f2bf_bits(h1);
                o2 = f2bf_bits(h2); o3 = f2bf_bits(h3);
                ushort4 ho; ho.x = o0; ho.y = o1; ho.z = o2; ho.w = o3;
                *(ushort4*)&hb[g] = ho;
            }
            unsigned short* dst = &As[row * AST_L + c4];
            dst[0] = o0; dst[1] = o1; dst[2] = o2; dst[3] = o3;
        }
    }
    __syncthreads();
    int lane = t & 63, w = t >> 6;
    int m = lane & 15, quad = lane >> 4;
    int rl = w * 32;
    int rbase = r0 + rl;
    bf16x8 a[2][4];
    #pragma unroll
    for (int rt = 0; rt < 2; ++rt)
        #pragma unroll
        for (int c = 0; c < 4; ++c)
            a[rt][c] = *(const bf16x8*)(As + (rl + rt * 16 + m) * AST_L + c * 32 + quad * 8);
    float dv[2][4];
    #pragma unroll
    for (int rt = 0; rt < 2; ++rt)
        #pragma unroll
        for (int rg = 0; rg < 4; ++rg) {
            int row = rbase + rt * 16 + quad * 4 + rg; if (row > n - 1) row = n - 1;
            dv[rt][rg] = dinv[row];
        }
    f32x4 acc[2][8];
    #pragma unroll
    for (int t8 = 0; t8 < 8; ++t8) {
        f32x4 z = {0.f, 0.f, 0.f, 0.f};
        acc[0][t8] = z; acc[1][t8] = z;
    }
    #pragma unroll
    for (int t8 = 0; t8 < 8; ++t8) {
        #pragma unroll
        for (int c = 0; c < 4; ++c) {
            bf16x8 b = *(const bf16x8*)(Wt + (long)(t8 * 16 + m) * DD + c * 32 + quad * 8);
            acc[0][t8] = __builtin_amdgcn_mfma_f32_16x16x32_bf16(a[0][c], b, acc[0][t8], 0, 0, 0);
            acc[1][t8] = __builtin_amdgcn_mfma_f32_16x16x32_bf16(a[1][c], b, acc[1][t8], 0, 0, 0);
        }
    }
    #pragma unroll
    for (int rt = 0; rt < 2; ++rt)
        #pragma unroll
        for (int t8 = 0; t8 < 8; ++t8)
            #pragma unroll
            for (int rg = 0; rg < 4; ++rg) {
                int row = rbase + rt * 16 + quad * 4 + rg;
                int col = t8 * 16 + m;
                if (row < n) Mb[(long)row * DD + col] = f2bf_bits(dv[rt][rg] * acc[rt][t8][rg]);
            }
}

// agg[i] = dinv[i] * (mbS[i] + sum_e mbS[src_s[e]]) + bias, fused stats.
// (R11-proven) Wave = 4 groups x 16 lanes; one dwordx4/lane fetches 4 edges'
// full 256B rows. Group-combine via per-wave LDS (stride-129, compile barriers).
__global__ __launch_bounds__(256) void agg_kernel(
    const unsigned short* __restrict__ mb, const int* __restrict__ off,
    const int* __restrict__ src_s, const float* __restrict__ dinv,
    const float* __restrict__ bias, float* __restrict__ agg,
    float* __restrict__ statacc)
{
    __shared__ float sred[4][4 * RST];
    __shared__ float2 ssum[4][64], ssq[4][64];
    int t = threadIdx.x;
    int wv = t >> 6, lane = t & 63;
    int grp = lane >> 4, sl = lane & 15;
    float* red = sred[wv];
    float2 bi = ((const float2*)bias)[lane];
    float2 sAcc = {0.0f, 0.0f}, qAcc = {0.0f, 0.0f};
    int i0 = (blockIdx.x * 4 + wv) * NPW;
    #pragma unroll 1
    for (int ni = 0; ni < NPW; ++ni) {
        int i = i0 + ni;
        if (i >= NN) break;
        float acc[8];
        #pragma unroll
        for (int k = 0; k < 8; ++k) acc[k] = 0.0f;
        if (grp == 0) {
            uint4 v = *(const uint4*)(mb + (long)i * DD + sl * 8);
            acc_add8(acc, v);
        }
        int e = off[i], e1 = off[i + 1];
        for (; e + 8 <= e1; e += 8) {
            int ja = src_s[e + grp];
            int jb = src_s[e + 4 + grp];
            uint4 va = *(const uint4*)(mb + (long)ja * DD + sl * 8);
            uint4 vb = *(const uint4*)(mb + (long)jb * DD + sl * 8);
            acc_add8(acc, va);
            acc_add8(acc, vb);
        }
        for (; e + 4 <= e1; e += 4) {
            int j = src_s[e + grp];
            uint4 v = *(const uint4*)(mb + (long)j * DD + sl * 8);
            acc_add8(acc, v);
        }
        if (e + grp < e1) {
            int j = src_s[e + grp];
            uint4 v = *(const uint4*)(mb + (long)j * DD + sl * 8);
            acc_add8(acc, v);
        }
        #pragma unroll
        for (int k = 0; k < 8; ++k) red[grp * RST + sl * 8 + k] = acc[k];
        asm volatile("" ::: "memory");
        float c0 = 0.0f, c1 = 0.0f;
        #pragma unroll
        for (int g = 0; g < 4; ++g) {
            c0 += red[g * RST + 2 * lane];
            c1 += red[g * RST + 2 * lane + 1];
        }
        asm volatile("" ::: "memory");
        float di = dinv[i];
        float2 outv;
        outv.x = di * c0 + bi.x;
        outv.y = di * c1 + bi.y;
        ((float2*)agg)[(long)i * 64 + lane] = outv;
        sAcc.x += outv.x; sAcc.y += outv.y;
        qAcc.x += outv.x * outv.x; qAcc.y += outv.y * outv.y;
    }
    ssum[wv][lane] = sAcc; ssq[wv][lane] = qAcc;
    __syncthreads();
    if (wv == 0) {
        float2 s0 = ssum[0][lane], s1 = ssum[1][lane], s2 = ssum[2][lane], s3 = ssum[3][lane];
        float2 q0 = ssq[0][lane], q1 = ssq[1][lane], q2 = ssq[2][lane], q3 = ssq[3][lane];
        float sx = s0.x + s1.x + s2.x + s3.x;
        float sy = s0.y + s1.y + s2.y + s3.y;
        float qx = q0.x + q1.x + q2.x + q3.x;
        float qy = q0.y + q1.y + q2.y + q3.y;
        float* copy = statacc + (blockIdx.x & (NCOPY - 1)) * 256;
        atomicAdd(&copy[2 * lane], sx);
        atomicAdd(&copy[2 * lane + 1], sy);
        atomicAdd(&copy[128 + 2 * lane], qx);
        atomicAdd(&copy[128 + 2 * lane + 1], qy);
    }
}

// pooling with inline stats-finalize + fused final BN+relu+residual (hb bf16)
__global__ void pool1_kernel(const unsigned short* __restrict__ hb,
                             const float* __restrict__ agg,
                             const float* __restrict__ statmulti,
                             const float* __restrict__ gamma, const float* __restrict__ beta,
                             const int* __restrict__ b32, float* __restrict__ hgsum, int n) {
    __shared__ float bnsh[256];
    int t = threadIdx.x;
    {
        float s = 0.0f;
        #pragma unroll 8
        for (int k = 0; k < NCOPY; ++k) s += statmulti[k * 256 + t];
        bnsh[t] = s;
    }
    __syncthreads();
    int c4 = (t & 31) * 4, rsub = t >> 5;
    float inv_n = 1.0f / (float)n;
    float4 sm = *(const float4*)&bnsh[c4];
    float4 sq = *(const float4*)&bnsh[128 + c4];
    float4 ga = *(const float4*)&gamma[c4];
    float4 be = *(const float4*)&beta[c4];
    float4 mu, rs;
    mu.x = sm.x * inv_n; mu.y = sm.y * inv_n; mu.z = sm.z * inv_n; mu.w = sm.w * inv_n;
    rs.x = rsqrtf(sq.x * inv_n - mu.x * mu.x + BN_EPS) * ga.x;
    rs.y = rsqrtf(sq.y * inv_n - mu.y * mu.y + BN_EPS) * ga.y;
    rs.z = rsqrtf(sq.z * inv_n - mu.z * mu.z + BN_EPS) * ga.z;
    rs.w = rsqrtf(sq.w * inv_n - mu.w * mu.w + BN_EPS) * ga.w;
    int rows_pb = (n + gridDim.x - 1) / gridDim.x;
    int r0 = blockIdx.x * rows_pb;
    int r1 = min(n, r0 + rows_pb);
    float4 acc = {0, 0, 0, 0};
    int gcur = -1;
    for (int r = r0 + rsub; r < r1; r += 8) {
        int g = b32[r];
        if (g != gcur) {
            if (gcur >= 0) {
                atomicAdd(&hgsum[gcur * DD + c4 + 0], acc.x);
                atomicAdd(&hgsum[gcur * DD + c4 + 1], acc.y);
                atomicAdd(&hgsum[gcur * DD + c4 + 2], acc.z);
                atomicAdd(&hgsum[gcur * DD + c4 + 3], acc.w);
            }
            acc.x = acc.y = acc.z = acc.w = 0.0f;
            gcur = ((unsigned)g < (unsigned)GG) ? g : -1;
        }
        if (gcur >= 0) {
            long ix = (long)r * DD + c4;
            float4 av = *(const float4*)&agg[ix];
            ushort4 hu = *(const ushort4*)&hb[ix];
            acc.x += bfu2f(hu.x) + fmaxf((av.x - mu.x) * rs.x + be.x, 0.0f);
            acc.y += bfu2f(hu.y) + fmaxf((av.y - mu.y) * rs.y + be.y, 0.0f);
            acc.z += bfu2f(hu.z) + fmaxf((av.z - mu.z) * rs.z + be.z, 0.0f);
            acc.w += bfu2f(hu.w) + fmaxf((av.w - mu.w) * rs.w + be.w, 0.0f);
        }
    }
    if (gcur >= 0) {
        atomicAdd(&hgsum[gcur * DD + c4 + 0], acc.x);
        atomicAdd(&hgsum[gcur * DD + c4 + 1], acc.y);
        atomicAdd(&hgsum[gcur * DD + c4 + 2], acc.z);
        atomicAdd(&hgsum[gcur * DD + c4 + 3], acc.w);
    }
}

__device__ int lower_bound_i(const int* __restrict__ a, int n, int v) {
    int lo = 0, hi = n;
    while (lo < hi) {
        int mid = (lo + hi) >> 1;
        if (a[mid] < v) lo = mid + 1; else hi = mid;
    }
    return lo;
}

// readout with fused mean-pool finalize
__global__ void readout_kernel(const float* __restrict__ hgsum, const int* __restrict__ b32,
                               const float* __restrict__ W1, const float* __restrict__ b1,
                               const float* __restrict__ W2, const float* __restrict__ b2,
                               const float* __restrict__ W3, const float* __restrict__ b3,
                               const int* __restrict__ flags, void* __restrict__ out, int n) {
    int f32 = flags[2];
    int g = blockIdx.x;
    int t = threadIdx.x;
    __shared__ float hgs[DD];
    __shared__ float z1[DD / 2];
    __shared__ float z2[DD / 4];
    int lo = lower_bound_i(b32, n, g);
    int hi = lower_bound_i(b32, n, g + 1);
    float invc = 1.0f / fmaxf((float)(hi - lo), 1.0f);
    hgs[t] = hgsum[g * DD + t] * invc;
    __syncthreads();
    if (t < DD / 2) {
        float acc = b1[t];
        #pragma unroll 8
        for (int k = 0; k < DD; ++k) acc = fmaf(hgs[k], W1[k * (DD / 2) + t], acc);
        z1[t] = fmaxf(acc, 0.0f);
    }
    __syncthreads();
    if (t < DD / 4) {
        float acc = b2[t];
        #pragma unroll 8
        for (int k = 0; k < DD / 2; ++k) acc = fmaf(z1[k], W2[k * (DD / 4) + t], acc);
        z2[t] = fmaxf(acc, 0.0f);
    }
    __syncthreads();
    if (t < NC) {
        float acc = b3[t];
        #pragma unroll 8
        for (int k = 0; k < DD / 4; ++k) acc = fmaf(z2[k], W3[k * NC + t], acc);
        if (f32) ((float*)out)[g * NC + t] = acc;
        else     ((__hip_bfloat16*)out)[g * NC + t] = __float2bfloat16(acc);
    }
}

extern "C" void kernel_launch(void* const* d_in, const int* in_sizes, int n_in,
                              void* d_out, int out_size, void* d_ws, size_t ws_size,
                              hipStream_t stream) {
    const void* x      = d_in[0];
    const void* ei     = d_in[1];
    const void* batch  = d_in[2];
    const void* W_emb  = d_in[3];
    const void* b_emb  = d_in[4];
    const void* W_gcn  = d_in[5];
    const void* b_gcn  = d_in[6];
    const void* bn_g   = d_in[7];
    const void* bn_b   = d_in[8];
    const void* W_r1   = d_in[9];
    const void* b_r1   = d_in[10];
    const void* W_r2   = d_in[11];
    const void* b_r2   = d_in[12];
    const void* W_r3   = d_in[13];
    const void* b_r3   = d_in[14];

    char* p = (char*)d_ws;
    auto alloc = [&](size_t bytes) -> void* {
        void* r = (void*)p;
        p += (bytes + 255) & ~(size_t)255;
        return r;
    };
    int*   flags  = (int*)alloc(64 * 4);
    int*   deg    = (int*)alloc((size_t)NN * 4);
    float* statmulti = (float*)alloc((size_t)LL * NCOPY * 256 * 4);
    float* hgsum  = (float*)alloc((size_t)GG * DD * 4);
    int*   off    = (int*)alloc((size_t)(NN + 1) * 4);
    float* dinv   = (float*)alloc((size_t)NN * 4);
    int*   src32  = (int*)alloc((size_t)EE * 4);
    int*   dst32  = (int*)alloc((size_t)EE * 4);
    int*   rank   = (int*)alloc((size_t)EE * 4);
    int*   b32    = (int*)alloc((size_t)NN * 4);
    int*   src_s  = (int*)alloc((size_t)EE * 4);
    int*   bsum   = (int*)alloc(256 * 4);
    int*   boff   = (int*)alloc(256 * 4);
    unsigned short* hb = (unsigned short*)alloc((size_t)NN * DD * 2);
    unsigned short* mb = (unsigned short*)alloc((size_t)NN * DD * 2);
    float* agg    = (float*)alloc((size_t)NN * DD * 4);
    // xb aliases agg: xb (16MB bf16) only live before first agg write
    unsigned short* xb = (unsigned short*)agg;
    // canonical params
    unsigned short* wt_emb = (unsigned short*)alloc((size_t)DD * KP_EMB * 2);
    unsigned short* wt_gcn = (unsigned short*)alloc((size_t)LL * DD * DD * 2);
    float* b_emb32 = (float*)alloc(DD * 4);
    float* b_gcn32 = (float*)alloc((size_t)LL * DD * 4);
    float* bng32   = (float*)alloc((size_t)LL * DD * 4);
    float* bnb32   = (float*)alloc((size_t)LL * DD * 4);
    float* wr1     = (float*)alloc((size_t)DD * (DD / 2) * 4);
    float* br1     = (float*)alloc((DD / 2) * 4);
    float* wr2     = (float*)alloc((size_t)(DD / 2) * (DD / 4) * 4);
    float* br2     = (float*)alloc((DD / 4) * 4);
    float* wr3     = (float*)alloc((size_t)(DD / 4) * NC * 4);
    float* br3     = (float*)alloc(NC * 4);

    detect_kernel<<<1, 64, 0, stream>>>(ei, batch, W_emb, flags);

    Params12 P;
    P.p[0]  = { b_emb, b_emb32, DD, DD };
    P.p[1]  = { b_gcn, b_gcn32, LL * DD, LL * DD };
    P.p[2]  = { bn_g,  bng32,   LL * DD, LL * DD };
    P.p[3]  = { bn_b,  bnb32,   LL * DD, LL * DD };
    P.p[4]  = { W_r1,  wr1,     DD * (DD / 2), DD * (DD / 2) };
    P.p[5]  = { b_r1,  br1,     DD / 2, DD / 2 };
    P.p[6]  = { W_r2,  wr2,     (DD / 2) * (DD / 4), (DD / 2) * (DD / 4) };
    P.p[7]  = { b_r2,  br2,     DD / 4, DD / 4 };
    P.p[8]  = { W_r3,  wr3,     (DD / 4) * NC, (DD / 4) * NC };
    P.p[9]  = { b_r3,  br3,     NC, NC };
    P.p[10] = { b_r3,  br3,     0, 0 };
    P.p[11] = { b_r3,  br3,     0, 0 };

    WtDescs5 W;
    W.p[0] = { W_emb, 0,            wt_emb,                DIN, KP_EMB };
    W.p[1] = { W_gcn, 0L * DD * DD, wt_gcn + 0L * DD * DD, DD,  DD };
    W.p[2] = { W_gcn, 1L * DD * DD, wt_gcn + 1L * DD * DD, DD,  DD };
    W.p[3] = { W_gcn, 2L * DD * DD, wt_gcn + 2L * DD * DD, DD,  DD };
    W.p[4] = { W_gcn, 3L * DD * DD, wt_gcn + 3L * DD * DD, DD,  DD };

    mega_conv_kernel<<<C_WT, 256, 0, stream>>>(x, batch, flags, xb, deg, statmulti,
                                               hgsum, b32, P, W);

    edge_emb_kernel<<<B_TOT, 256, 0, stream>>>(ei, flags, src32, dst32, rank, deg,
                                               xb, wt_emb, b_emb32, hb, NN);

    int nb = (NN + 255) / 256;  // 196
    scan1_kernel<<<nb, 256, 0, stream>>>(deg, off, bsum, dinv, NN);
    scan2_kernel<<<1, 256, 0, stream>>>(bsum, boff, off + NN, nb);
    scan3_kernel<<<nb, 256, 0, stream>>>(off, boff, NN);

    scat_mm_kernel<<<S_TOT, 256, 0, stream>>>(src32, dst32, rank, off, src_s,
                                              hb, wt_gcn, dinv, mb, NN);

    int ngemm = (NN + 127) / 128;  // 391
    int nagg = (NN + 4 * NPW - 1) / (4 * NPW);  // 3125 blocks (16 nodes/block)
    for (int l = 0; l < LL; ++l) {
        if (l > 0) {
            gemm_fused_kernel<<<ngemm, 256, 0, stream>>>(
                agg, hb, statmulti + (size_t)(l - 1) * NCOPY * 256,
                bng32 + (l - 1) * DD, bnb32 + (l - 1) * DD,
                dinv, wt_gcn + (size_t)l * DD * DD, mb, NN);
        }
        agg_kernel<<<nagg, 256, 0, stream>>>(mb, off, src_s, dinv,
                                             b_gcn32 + l * DD, agg,
                                             statmulti + (size_t)l * NCOPY * 256);
    }

    pool1_kernel<<<512, 256, 0, stream>>>(hb, agg, statmulti + (size_t)(LL - 1) * NCOPY * 256,
                                          bng32 + (LL - 1) * DD, bnb32 + (LL - 1) * DD,
                                          b32, hgsum, NN);
    readout_kernel<<<GG, DD, 0, stream>>>(hgsum, b32, wr1, br1, wr2, br2, wr3, br3,
                                          flags, d_out, NN);
}

// Round 14
// 444.858 us; speedup vs baseline: 1.8639x; 1.0189x over previous
//
#include <hip/hip_runtime.h>
#include <hip/hip_bf16.h>

// Problem constants (fixed by the reference)
#define NN 50000
#define EE 800000
#define DIN 146
#define DD 128
#define GG 64
#define LL 4
#define NC 10
#define BN_EPS 1e-5f

#define KP_EMB 160    // 146 padded to multiple of 32
#define AST_L  136    // LDS A stride (shorts) for fused gemm
#define NCOPY 64      // stat accumulator copies (contention spreading)
#define NPW 4         // nodes per wave in agg
#define RST 129       // agg LDS group stride (floats)

// mega_conv block ranges: init / repack / batch / params / wt
#define C_INIT   256
#define C_REPACK (C_INIT + 31250)
#define C_BATCH  (C_REPACK + 196)
#define C_PARAMS (C_BATCH + 384)
#define C_WT     (C_PARAMS + 400)

// edge_emb: edge conv (3125) + emb gemm (391)
#define B_EDGE 3125
#define B_TOT  (B_EDGE + 391)
// scat_mm: scatter (3125) + gemm_plain (391)
#define S_SCAT 3125
#define S_TOT  (S_SCAT + 391)

typedef __attribute__((ext_vector_type(8))) short bf16x8;
typedef __attribute__((ext_vector_type(4))) float f32x4;

__device__ __forceinline__ float bf2f(__hip_bfloat16 v) { return __bfloat162float(v); }
__device__ __forceinline__ float loadf(const void* p, long i, int f32) {
    return f32 ? ((const float*)p)[i] : bf2f(((const __hip_bfloat16*)p)[i]);
}
__device__ __forceinline__ unsigned short f2bf_bits(float f) {
    __hip_bfloat16 h = __float2bfloat16(f);
    return *(unsigned short*)&h;
}
__device__ __forceinline__ float bfu2f(unsigned short u) {
    return __uint_as_float((unsigned)u << 16);
}
__device__ __forceinline__ void acc_add8(float* acc, uint4 v) {
    acc[0] += __uint_as_float(v.x << 16);
    acc[1] += __uint_as_float(v.x & 0xffff0000u);
    acc[2] += __uint_as_float(v.y << 16);
    acc[3] += __uint_as_float(v.y & 0xffff0000u);
    acc[4] += __uint_as_float(v.z << 16);
    acc[5] += __uint_as_float(v.z & 0xffff0000u);
    acc[6] += __uint_as_float(v.w << 16);
    acc[7] += __uint_as_float(v.w & 0xffff0000u);
}

// flags[0]=edge_index int64, flags[1]=batch int64, flags[2]=floats are f32
__global__ void detect_kernel(const void* ei, const void* batch, const void* Wemb,
                              int* __restrict__ flags) {
    __shared__ int s_edge_nz, s_batch_nz, s_f32_cnt;
    int t = threadIdx.x;  // 64
    if (t == 0) { s_edge_nz = 0; s_batch_nz = 0; s_f32_cnt = 0; }
    __syncthreads();
    {   const int* w = (const int*)ei;
        long j = ((long)t * ((2L * EE) / 64)) | 1;
        if (w[j] != 0) atomicAdd(&s_edge_nz, 1);
    }
    {   const int* w = (const int*)batch;
        long j = ((long)(NN / 2) + (long)t * ((NN / 2) / 64)) | 1;
        if (j < NN && w[j] != 0) atomicAdd(&s_batch_nz, 1);
    }
    {   const unsigned short* w = (const unsigned short*)Wemb;
        unsigned short v = w[2 * t];
        int ex = (v >> 7) & 0xFF;
        if (v != 0 && ex >= 128) atomicAdd(&s_f32_cnt, 1);
    }
    __syncthreads();
    if (t == 0) {
        flags[0] = (s_edge_nz == 0) ? 1 : 0;
        flags[1] = (s_batch_nz == 0) ? 1 : 0;
        flags[2] = (s_f32_cnt >= 8) ? 1 : 0;
    }
}

struct Param { const void* src; float* dst; int src_n; int dst_n; };
struct Params12 { Param p[12]; };
struct WtDesc { const void* src; long src_off; unsigned short* dst; int K; int Kpad; };
struct WtDescs5 { WtDesc p[5]; };

// merged conversions + zero-init (no atomics; all independent)
__global__ __launch_bounds__(256) void mega_conv_kernel(
    const void* __restrict__ x, const void* __restrict__ batch,
    const int* __restrict__ flags, unsigned short* __restrict__ xb,
    int* __restrict__ deg, float* __restrict__ statmulti, float* __restrict__ hgsum,
    int* __restrict__ b32, Params12 P, WtDescs5 W)
{
    int b = blockIdx.x;
    int t = threadIdx.x;
    if (b < C_INIT) {
        int i = b * 256 + t;
        if (i < NN) deg[i] = 0;
        if (i < LL * NCOPY * 256) statmulti[i] = 0.0f;
        if (i < GG * DD) hgsum[i] = 0.0f;
    } else if (b < C_REPACK) {
        int f32 = flags[2];
        long idx = (long)(b - C_INIT) * 256 + t;  // < 8,000,000 exactly
        int row = (int)(idx / KP_EMB);
        int k = (int)(idx - (long)row * KP_EMB);
        float v = (k < DIN) ? loadf(x, (long)row * DIN + k, f32) : 0.0f;
        xb[idx] = f2bf_bits(v);
    } else if (b < C_BATCH) {
        int i = (b - C_REPACK) * 256 + t;
        if (i < NN) b32[i] = flags[1] ? ((const int*)batch)[2L * i] : ((const int*)batch)[i];
    } else if (b < C_PARAMS) {
        int f32 = flags[2];
        int bb = b - C_BATCH;
        const Param& e = P.p[bb >> 5];
        int idx = (bb & 31) * 256 + t;
        if (idx < e.dst_n)
            e.dst[idx] = (idx < e.src_n) ? loadf(e.src, idx, f32) : 0.0f;
    } else {
        int f32 = flags[2];
        int bb = b - C_PARAMS;
        int y = bb / 80;
        const WtDesc& e = W.p[y];
        int idx = (bb - y * 80) * 256 + t;
        if (idx < 128 * e.Kpad) {
            int n = idx / e.Kpad, k = idx - n * e.Kpad;
            float v = (k < e.K) ? loadf(e.src, e.src_off + (long)k * DD + n, f32) : 0.0f;
            e.dst[idx] = f2bf_bits(v);
        }
    }
}

// ---- MFMA layouts ----
// A frag: m=lane&15, k=quad*8+j   B frag (from W^T): n=lane&15, k=quad*8+j
// C/D:    col=lane&15, row=quad*4+reg

// merged: edge conv+deg+rank (latency-bound atomics) || emb MFMA gemm (hb bf16)
__global__ __launch_bounds__(256) void edge_emb_kernel(
    const void* __restrict__ ei, const int* __restrict__ flags,
    int* __restrict__ src32, int* __restrict__ dst32,
    int* __restrict__ rank, int* __restrict__ deg,
    const unsigned short* __restrict__ Ab,   // xb [n][160] bf16
    const unsigned short* __restrict__ Wt,   // [128][160] bf16 transposed
    const float* __restrict__ bias,
    unsigned short* __restrict__ hb, int n)
{
    int t = threadIdx.x;
    if (blockIdx.x < B_EDGE) {
        int e = blockIdx.x * 256 + t;  // < 800000 exactly
        const int* w = (const int*)ei;
        int s, d;
        if (flags[0]) { s = w[2L * e]; d = w[2L * (EE + e)]; }
        else          { s = w[e];      d = w[EE + e]; }
        src32[e] = s; dst32[e] = d;
        int r = 0;
        if ((unsigned)d < (unsigned)NN) r = atomicAdd(&deg[d], 1);
        rank[e] = r;
        return;
    }
    int r0 = (blockIdx.x - B_EDGE) * 128;
    int lane = t & 63, w = t >> 6;
    int m = lane & 15, quad = lane >> 4;
    int rbase = r0 + w * 32;
    bf16x8 a[2][5];
    #pragma unroll
    for (int rt = 0; rt < 2; ++rt)
        #pragma unroll
        for (int c = 0; c < 5; ++c) {
            int rr = rbase + rt * 16 + m; if (rr > n - 1) rr = n - 1;
            a[rt][c] = *(const bf16x8*)(Ab + (long)rr * KP_EMB + c * 32 + quad * 8);
        }
    f32x4 acc[2][8];
    #pragma unroll
    for (int t8 = 0; t8 < 8; ++t8) {
        float bv = bias[t8 * 16 + m];
        f32x4 ai = {bv, bv, bv, bv};
        acc[0][t8] = ai; acc[1][t8] = ai;
    }
    #pragma unroll
    for (int t8 = 0; t8 < 8; ++t8) {
        #pragma unroll
        for (int c = 0; c < 5; ++c) {
            bf16x8 b = *(const bf16x8*)(Wt + (long)(t8 * 16 + m) * KP_EMB + c * 32 + quad * 8);
            acc[0][t8] = __builtin_amdgcn_mfma_f32_16x16x32_bf16(a[0][c], b, acc[0][t8], 0, 0, 0);
            acc[1][t8] = __builtin_amdgcn_mfma_f32_16x16x32_bf16(a[1][c], b, acc[1][t8], 0, 0, 0);
        }
    }
    #pragma unroll
    for (int rt = 0; rt < 2; ++rt)
        #pragma unroll
        for (int t8 = 0; t8 < 8; ++t8)
            #pragma unroll
            for (int rg = 0; rg < 4; ++rg) {
                int row = rbase + rt * 16 + quad * 4 + rg;
                int col = t8 * 16 + m;
                if (row < n) hb[(long)row * DD + col] = f2bf_bits(acc[rt][t8][rg]);
            }
}

// ---- 3-phase exclusive scan (dinv fused into phase 1) ----
__global__ void scan1_kernel(const int* __restrict__ cnt, int* __restrict__ off,
                             int* __restrict__ bsum, float* __restrict__ dinv, int n) {
    int t = threadIdx.x;
    int i = blockIdx.x * 256 + t;
    int v = (i < n) ? cnt[i] : 0;
    if (i < n) dinv[i] = rsqrtf((float)(v + 1));  // +1 self-loop
    int lane = t & 63, w = t >> 6;
    int x = v;
    #pragma unroll
    for (int s = 1; s < 64; s <<= 1) {
        int y = __shfl_up(x, s, 64);
        if (lane >= s) x += y;
    }
    __shared__ int wsum[4];
    if (lane == 63) wsum[w] = x;
    __syncthreads();
    if (t == 0) {
        int a = 0;
        #pragma unroll
        for (int k = 0; k < 4; ++k) { int tmp = wsum[k]; wsum[k] = a; a += tmp; }
        bsum[blockIdx.x] = a;
    }
    __syncthreads();
    int excl = x - v + wsum[w];
    if (i < n) off[i] = excl;
}

__global__ void scan2_kernel(int* __restrict__ bsum, int* __restrict__ boff,
                             int* __restrict__ off_last, int nb) {
    int t = threadIdx.x;  // 256
    int v = (t < nb) ? bsum[t] : 0;
    int lane = t & 63, w = t >> 6;
    int x = v;
    #pragma unroll
    for (int s = 1; s < 64; s <<= 1) {
        int y = __shfl_up(x, s, 64);
        if (lane >= s) x += y;
    }
    __shared__ int wsum[4];
    if (lane == 63) wsum[w] = x;
    __syncthreads();
    __shared__ int total_s;
    if (t == 0) {
        int a = 0;
        #pragma unroll
        for (int k = 0; k < 4; ++k) { int tmp = wsum[k]; wsum[k] = a; a += tmp; }
        total_s = a;
    }
    __syncthreads();
    if (t < nb) boff[t] = x - v + wsum[w];
    if (t == 0) *off_last = total_s;
}

__global__ void scan3_kernel(int* __restrict__ off, const int* __restrict__ boff, int n) {
    int i = blockIdx.x * 256 + threadIdx.x;
    if (i < n) off[i] += boff[blockIdx.x];
}

// merged: CSR scatter (latency-bound random writes) || layer-0 gemm_plain (MFMA)
__global__ __launch_bounds__(256) void scat_mm_kernel(
    const int* __restrict__ src, const int* __restrict__ dst,
    const int* __restrict__ rank, const int* __restrict__ off,
    int* __restrict__ src_s,
    const unsigned short* __restrict__ Ab,   // hb
    const unsigned short* __restrict__ Wt,   // wt_gcn layer 0
    const float* __restrict__ dinv,
    unsigned short* __restrict__ Mb, int n)
{
    int t = threadIdx.x;
    if (blockIdx.x < S_SCAT) {
        int e = blockIdx.x * 256 + t;  // < 800000 exactly
        int s = src[e], d = dst[e];
        if ((unsigned)s >= (unsigned)NN || (unsigned)d >= (unsigned)NN) return;
        src_s[off[d] + rank[e]] = s;
        return;
    }
    int r0 = (blockIdx.x - S_SCAT) * 128;
    int lane = t & 63, w = t >> 6;
    int m = lane & 15, quad = lane >> 4;
    int rbase = r0 + w * 32;
    bf16x8 a[2][4];
    #pragma unroll
    for (int rt = 0; rt < 2; ++rt)
        #pragma unroll
        for (int c = 0; c < 4; ++c) {
            int rr = rbase + rt * 16 + m; if (rr > n - 1) rr = n - 1;
            a[rt][c] = *(const bf16x8*)(Ab + (long)rr * DD + c * 32 + quad * 8);
        }
    float dv[2][4];
    #pragma unroll
    for (int rt = 0; rt < 2; ++rt)
        #pragma unroll
        for (int rg = 0; rg < 4; ++rg) {
            int row = rbase + rt * 16 + quad * 4 + rg; if (row > n - 1) row = n - 1;
            dv[rt][rg] = dinv[row];
        }
    f32x4 acc[2][8];
    #pragma unroll
    for (int t8 = 0; t8 < 8; ++t8) {
        f32x4 z = {0.f, 0.f, 0.f, 0.f};
        acc[0][t8] = z; acc[1][t8] = z;
    }
    #pragma unroll
    for (int t8 = 0; t8 < 8; ++t8) {
        #pragma unroll
        for (int c = 0; c < 4; ++c) {
            bf16x8 b = *(const bf16x8*)(Wt + (long)(t8 * 16 + m) * DD + c * 32 + quad * 8);
            acc[0][t8] = __builtin_amdgcn_mfma_f32_16x16x32_bf16(a[0][c], b, acc[0][t8], 0, 0, 0);
            acc[1][t8] = __builtin_amdgcn_mfma_f32_16x16x32_bf16(a[1][c], b, acc[1][t8], 0, 0, 0);
        }
    }
    #pragma unroll
    for (int rt = 0; rt < 2; ++rt)
        #pragma unroll
        for (int t8 = 0; t8 < 8; ++t8)
            #pragma unroll
            for (int rg = 0; rg < 4; ++rg) {
                int row = rbase + rt * 16 + quad * 4 + rg;
                int col = t8 * 16 + m;
                if (row < n) Mb[(long)row * DD + col] = f2bf_bits(dv[rt][rg] * acc[rt][t8][rg]);
            }
}

// fused: inline stats-finalize + hb += relu(bn(aggb)) (bf16 in-place) + MFMA
__global__ __launch_bounds__(256) void gemm_fused_kernel(
    const unsigned short* __restrict__ aggb, unsigned short* __restrict__ hb,
    const float* __restrict__ statmulti, const float* __restrict__ gamma,
    const float* __restrict__ beta, const float* __restrict__ dinv,
    const unsigned short* __restrict__ Wt, unsigned short* __restrict__ Mb, int n)
{
    __shared__ unsigned short As[128 * AST_L];
    __shared__ float bnsh[256];
    int t = threadIdx.x;
    int r0 = blockIdx.x * 128;
    {
        float s = 0.0f;
        #pragma unroll 8
        for (int k = 0; k < NCOPY; ++k) s += statmulti[k * 256 + t];
        bnsh[t] = s;
    }
    __syncthreads();
    {
        int c4 = (t & 31) * 4, rsub = t >> 5;  // 8 row substreams
        float inv_n = 1.0f / (float)n;
        float4 sm = *(const float4*)&bnsh[c4];
        float4 sq = *(const float4*)&bnsh[128 + c4];
        float4 ga = *(const float4*)&gamma[c4];
        float4 be = *(const float4*)&beta[c4];
        float4 mu, rs;
        mu.x = sm.x * inv_n; mu.y = sm.y * inv_n; mu.z = sm.z * inv_n; mu.w = sm.w * inv_n;
        rs.x = rsqrtf(sq.x * inv_n - mu.x * mu.x + BN_EPS) * ga.x;
        rs.y = rsqrtf(sq.y * inv_n - mu.y * mu.y + BN_EPS) * ga.y;
        rs.z = rsqrtf(sq.z * inv_n - mu.z * mu.z + BN_EPS) * ga.z;
        rs.w = rsqrtf(sq.w * inv_n - mu.w * mu.w + BN_EPS) * ga.w;
        #pragma unroll 4
        for (int i = 0; i < 16; ++i) {
            int row = i * 8 + rsub;
            int r = r0 + row;
            unsigned short o0 = 0, o1 = 0, o2 = 0, o3 = 0;
            if (r < n) {
                long g = (long)r * DD + c4;
                ushort4 au = *(const ushort4*)&aggb[g];
                ushort4 hu = *(const ushort4*)&hb[g];
                float h0 = bfu2f(hu.x) + fmaxf((bfu2f(au.x) - mu.x) * rs.x + be.x, 0.0f);
                float h1 = bfu2f(hu.y) + fmaxf((bfu2f(au.y) - mu.y) * rs.y + be.y, 0.0f);
                float h2 = bfu2f(hu.z) + fmaxf((bfu2f(au.z) - mu.z) * rs.z + be.z, 0.0f);
                float h3 = bfu2f(hu.w) + fmaxf((bfu2f(au.w) - mu.w) * rs.w + be.w, 0.0f);
                o0 = f2bf_bits(h0); o1 = f2bf_bits(h1);
                o2 = f2bf_bits(h2); o3 = f2bf_bits(h3);
                ushort4 ho; ho.x = o0; ho.y = o1; ho.z = o2; ho.w = o3;
                *(ushort4*)&hb[g] = ho;
            }
            unsigned short* dst = &As[row * AST_L + c4];
            dst[0] = o0; dst[1] = o1; dst[2] = o2; dst[3] = o3;
        }
    }
    __syncthreads();
    int lane = t & 63, w = t >> 6;
    int m = lane & 15, quad = lane >> 4;
    int rl = w * 32;
    int rbase = r0 + rl;
    bf16x8 a[2][4];
    #pragma unroll
    for (int rt = 0; rt < 2; ++rt)
        #pragma unroll
        for (int c = 0; c < 4; ++c)
            a[rt][c] = *(const bf16x8*)(As + (rl + rt * 16 + m) * AST_L + c * 32 + quad * 8);
    float dv[2][4];
    #pragma unroll
    for (int rt = 0; rt < 2; ++rt)
        #pragma unroll
        for (int rg = 0; rg < 4; ++rg) {
            int row = rbase + rt * 16 + quad * 4 + rg; if (row > n - 1) row = n - 1;
            dv[rt][rg] = dinv[row];
        }
    f32x4 acc[2][8];
    #pragma unroll
    for (int t8 = 0; t8 < 8; ++t8) {
        f32x4 z = {0.f, 0.f, 0.f, 0.f};
        acc[0][t8] = z; acc[1][t8] = z;
    }
    #pragma unroll
    for (int t8 = 0; t8 < 8; ++t8) {
        #pragma unroll
        for (int c = 0; c < 4; ++c) {
            bf16x8 b = *(const bf16x8*)(Wt + (long)(t8 * 16 + m) * DD + c * 32 + quad * 8);
            acc[0][t8] = __builtin_amdgcn_mfma_f32_16x16x32_bf16(a[0][c], b, acc[0][t8], 0, 0, 0);
            acc[1][t8] = __builtin_amdgcn_mfma_f32_16x16x32_bf16(a[1][c], b, acc[1][t8], 0, 0, 0);
        }
    }
    #pragma unroll
    for (int rt = 0; rt < 2; ++rt)
        #pragma unroll
        for (int t8 = 0; t8 < 8; ++t8)
            #pragma unroll
            for (int rg = 0; rg < 4; ++rg) {
                int row = rbase + rt * 16 + quad * 4 + rg;
                int col = t8 * 16 + m;
                if (row < n) Mb[(long)row * DD + col] = f2bf_bits(dv[rt][rg] * acc[rt][t8][rg]);
            }
}

// aggb[i] = bf16( dinv[i] * (mbS[i] + sum_e mbS[src_s[e]]) + bias ), fused stats.
// Wave = 4 groups x 16 lanes; one dwordx4/lane fetches 4 edges' full 256B rows.
__global__ __launch_bounds__(256) void agg_kernel(
    const unsigned short* __restrict__ mb, const int* __restrict__ off,
    const int* __restrict__ src_s, const float* __restrict__ dinv,
    const float* __restrict__ bias, unsigned short* __restrict__ aggb,
    float* __restrict__ statacc)
{
    __shared__ float sred[4][4 * RST];
    __shared__ float2 ssum[4][64], ssq[4][64];
    int t = threadIdx.x;
    int wv = t >> 6, lane = t & 63;
    int grp = lane >> 4, sl = lane & 15;
    float* red = sred[wv];
    float2 bi = ((const float2*)bias)[lane];
    float2 sAcc = {0.0f, 0.0f}, qAcc = {0.0f, 0.0f};
    int i0 = (blockIdx.x * 4 + wv) * NPW;
    #pragma unroll 1
    for (int ni = 0; ni < NPW; ++ni) {
        int i = i0 + ni;
        if (i >= NN) break;
        float acc[8];
        #pragma unroll
        for (int k = 0; k < 8; ++k) acc[k] = 0.0f;
        if (grp == 0) {
            uint4 v = *(const uint4*)(mb + (long)i * DD + sl * 8);
            acc_add8(acc, v);
        }
        int e = off[i], e1 = off[i + 1];
        for (; e + 8 <= e1; e += 8) {
            int ja = src_s[e + grp];
            int jb = src_s[e + 4 + grp];
            uint4 va = *(const uint4*)(mb + (long)ja * DD + sl * 8);
            uint4 vb = *(const uint4*)(mb + (long)jb * DD + sl * 8);
            acc_add8(acc, va);
            acc_add8(acc, vb);
        }
        for (; e + 4 <= e1; e += 4) {
            int j = src_s[e + grp];
            uint4 v = *(const uint4*)(mb + (long)j * DD + sl * 8);
            acc_add8(acc, v);
        }
        if (e + grp < e1) {
            int j = src_s[e + grp];
            uint4 v = *(const uint4*)(mb + (long)j * DD + sl * 8);
            acc_add8(acc, v);
        }
        #pragma unroll
        for (int k = 0; k < 8; ++k) red[grp * RST + sl * 8 + k] = acc[k];
        asm volatile("" ::: "memory");
        float c0 = 0.0f, c1 = 0.0f;
        #pragma unroll
        for (int g = 0; g < 4; ++g) {
            c0 += red[g * RST + 2 * lane];
            c1 += red[g * RST + 2 * lane + 1];
        }
        asm volatile("" ::: "memory");
        float di = dinv[i];
        float o0 = di * c0 + bi.x;
        float o1 = di * c1 + bi.y;
        unsigned packed = ((unsigned)f2bf_bits(o1) << 16) | f2bf_bits(o0);
        ((unsigned*)aggb)[(long)i * 64 + lane] = packed;
        sAcc.x += o0; sAcc.y += o1;
        qAcc.x += o0 * o0; qAcc.y += o1 * o1;
    }
    ssum[wv][lane] = sAcc; ssq[wv][lane] = qAcc;
    __syncthreads();
    if (wv == 0) {
        float2 s0 = ssum[0][lane], s1 = ssum[1][lane], s2 = ssum[2][lane], s3 = ssum[3][lane];
        float2 q0 = ssq[0][lane], q1 = ssq[1][lane], q2 = ssq[2][lane], q3 = ssq[3][lane];
        float sx = s0.x + s1.x + s2.x + s3.x;
        float sy = s0.y + s1.y + s2.y + s3.y;
        float qx = q0.x + q1.x + q2.x + q3.x;
        float qy = q0.y + q1.y + q2.y + q3.y;
        float* copy = statacc + (blockIdx.x & (NCOPY - 1)) * 256;
        atomicAdd(&copy[2 * lane], sx);
        atomicAdd(&copy[2 * lane + 1], sy);
        atomicAdd(&copy[128 + 2 * lane], qx);
        atomicAdd(&copy[128 + 2 * lane + 1], qy);
    }
}

// pooling with inline stats-finalize + fused final BN+relu+residual (bf16 inputs)
__global__ void pool1_kernel(const unsigned short* __restrict__ hb,
                             const unsigned short* __restrict__ aggb,
                             const float* __restrict__ statmulti,
                             const float* __restrict__ gamma, const float* __restrict__ beta,
                             const int* __restrict__ b32, float* __restrict__ hgsum, int n) {
    __shared__ float bnsh[256];
    int t = threadIdx.x;
    {
        float s = 0.0f;
        #pragma unroll 8
        for (int k = 0; k < NCOPY; ++k) s += statmulti[k * 256 + t];
        bnsh[t] = s;
    }
    __syncthreads();
    int c4 = (t & 31) * 4, rsub = t >> 5;
    float inv_n = 1.0f / (float)n;
    float4 sm = *(const float4*)&bnsh[c4];
    float4 sq = *(const float4*)&bnsh[128 + c4];
    float4 ga = *(const float4*)&gamma[c4];
    float4 be = *(const float4*)&beta[c4];
    float4 mu, rs;
    mu.x = sm.x * inv_n; mu.y = sm.y * inv_n; mu.z = sm.z * inv_n; mu.w = sm.w * inv_n;
    rs.x = rsqrtf(sq.x * inv_n - mu.x * mu.x + BN_EPS) * ga.x;
    rs.y = rsqrtf(sq.y * inv_n - mu.y * mu.y + BN_EPS) * ga.y;
    rs.z = rsqrtf(sq.z * inv_n - mu.z * mu.z + BN_EPS) * ga.z;
    rs.w = rsqrtf(sq.w * inv_n - mu.w * mu.w + BN_EPS) * ga.w;
    int rows_pb = (n + gridDim.x - 1) / gridDim.x;
    int r0 = blockIdx.x * rows_pb;
    int r1 = min(n, r0 + rows_pb);
    float4 acc = {0, 0, 0, 0};
    int gcur = -1;
    for (int r = r0 + rsub; r < r1; r += 8) {
        int g = b32[r];
        if (g != gcur) {
            if (gcur >= 0) {
                atomicAdd(&hgsum[gcur * DD + c4 + 0], acc.x);
                atomicAdd(&hgsum[gcur * DD + c4 + 1], acc.y);
                atomicAdd(&hgsum[gcur * DD + c4 + 2], acc.z);
                atomicAdd(&hgsum[gcur * DD + c4 + 3], acc.w);
            }
            acc.x = acc.y = acc.z = acc.w = 0.0f;
            gcur = ((unsigned)g < (unsigned)GG) ? g : -1;
        }
        if (gcur >= 0) {
            long ix = (long)r * DD + c4;
            ushort4 au = *(const ushort4*)&aggb[ix];
            ushort4 hu = *(const ushort4*)&hb[ix];
            acc.x += bfu2f(hu.x) + fmaxf((bfu2f(au.x) - mu.x) * rs.x + be.x, 0.0f);
            acc.y += bfu2f(hu.y) + fmaxf((bfu2f(au.y) - mu.y) * rs.y + be.y, 0.0f);
            acc.z += bfu2f(hu.z) + fmaxf((bfu2f(au.z) - mu.z) * rs.z + be.z, 0.0f);
            acc.w += bfu2f(hu.w) + fmaxf((bfu2f(au.w) - mu.w) * rs.w + be.w, 0.0f);
        }
    }
    if (gcur >= 0) {
        atomicAdd(&hgsum[gcur * DD + c4 + 0], acc.x);
        atomicAdd(&hgsum[gcur * DD + c4 + 1], acc.y);
        atomicAdd(&hgsum[gcur * DD + c4 + 2], acc.z);
        atomicAdd(&hgsum[gcur * DD + c4 + 3], acc.w);
    }
}

__device__ int lower_bound_i(const int* __restrict__ a, int n, int v) {
    int lo = 0, hi = n;
    while (lo < hi) {
        int mid = (lo + hi) >> 1;
        if (a[mid] < v) lo = mid + 1; else hi = mid;
    }
    return lo;
}

// readout with fused mean-pool finalize
__global__ void readout_kernel(const float* __restrict__ hgsum, const int* __restrict__ b32,
                               const float* __restrict__ W1, const float* __restrict__ b1,
                               const float* __restrict__ W2, const float* __restrict__ b2,
                               const float* __restrict__ W3, const float* __restrict__ b3,
                               const int* __restrict__ flags, void* __restrict__ out, int n) {
    int f32 = flags[2];
    int g = blockIdx.x;
    int t = threadIdx.x;
    __shared__ float hgs[DD];
    __shared__ float z1[DD / 2];
    __shared__ float z2[DD / 4];
    int lo = lower_bound_i(b32, n, g);
    int hi = lower_bound_i(b32, n, g + 1);
    float invc = 1.0f / fmaxf((float)(hi - lo), 1.0f);
    hgs[t] = hgsum[g * DD + t] * invc;
    __syncthreads();
    if (t < DD / 2) {
        float acc = b1[t];
        #pragma unroll 8
        for (int k = 0; k < DD; ++k) acc = fmaf(hgs[k], W1[k * (DD / 2) + t], acc);
        z1[t] = fmaxf(acc, 0.0f);
    }
    __syncthreads();
    if (t < DD / 4) {
        float acc = b2[t];
        #pragma unroll 8
        for (int k = 0; k < DD / 2; ++k) acc = fmaf(z1[k], W2[k * (DD / 4) + t], acc);
        z2[t] = fmaxf(acc, 0.0f);
    }
    __syncthreads();
    if (t < NC) {
        float acc = b3[t];
        #pragma unroll 8
        for (int k = 0; k < DD / 4; ++k) acc = fmaf(z2[k], W3[k * NC + t], acc);
        if (f32) ((float*)out)[g * NC + t] = acc;
        else     ((__hip_bfloat16*)out)[g * NC + t] = __float2bfloat16(acc);
    }
}

extern "C" void kernel_launch(void* const* d_in, const int* in_sizes, int n_in,
                              void* d_out, int out_size, void* d_ws, size_t ws_size,
                              hipStream_t stream) {
    const void* x      = d_in[0];
    const void* ei     = d_in[1];
    const void* batch  = d_in[2];
    const void* W_emb  = d_in[3];
    const void* b_emb  = d_in[4];
    const void* W_gcn  = d_in[5];
    const void* b_gcn  = d_in[6];
    const void* bn_g   = d_in[7];
    const void* bn_b   = d_in[8];
    const void* W_r1   = d_in[9];
    const void* b_r1   = d_in[10];
    const void* W_r2   = d_in[11];
    const void* b_r2   = d_in[12];
    const void* W_r3   = d_in[13];
    const void* b_r3   = d_in[14];

    char* p = (char*)d_ws;
    auto alloc = [&](size_t bytes) -> void* {
        void* r = (void*)p;
        p += (bytes + 255) & ~(size_t)255;
        return r;
    };
    int*   flags  = (int*)alloc(64 * 4);
    int*   deg    = (int*)alloc((size_t)NN * 4);
    float* statmulti = (float*)alloc((size_t)LL * NCOPY * 256 * 4);
    float* hgsum  = (float*)alloc((size_t)GG * DD * 4);
    int*   off    = (int*)alloc((size_t)(NN + 1) * 4);
    float* dinv   = (float*)alloc((size_t)NN * 4);
    int*   src32  = (int*)alloc((size_t)EE * 4);
    int*   dst32  = (int*)alloc((size_t)EE * 4);
    int*   rank   = (int*)alloc((size_t)EE * 4);
    int*   b32    = (int*)alloc((size_t)NN * 4);
    int*   src_s  = (int*)alloc((size_t)EE * 4);
    int*   bsum   = (int*)alloc(256 * 4);
    int*   boff   = (int*)alloc(256 * 4);
    unsigned short* hb = (unsigned short*)alloc((size_t)NN * DD * 2);
    unsigned short* mb = (unsigned short*)alloc((size_t)NN * DD * 2);
    unsigned short* aggb = (unsigned short*)alloc((size_t)NN * DD * 2);
    // xb: separate buffer (16MB bf16), only live until edge_emb completes;
    // aliasing onto aggb would be fine too, but keep it distinct for clarity.
    unsigned short* xb = (unsigned short*)alloc((size_t)NN * KP_EMB * 2);
    // canonical params
    unsigned short* wt_emb = (unsigned short*)alloc((size_t)DD * KP_EMB * 2);
    unsigned short* wt_gcn = (unsigned short*)alloc((size_t)LL * DD * DD * 2);
    float* b_emb32 = (float*)alloc(DD * 4);
    float* b_gcn32 = (float*)alloc((size_t)LL * DD * 4);
    float* bng32   = (float*)alloc((size_t)LL * DD * 4);
    float* bnb32   = (float*)alloc((size_t)LL * DD * 4);
    float* wr1     = (float*)alloc((size_t)DD * (DD / 2) * 4);
    float* br1     = (float*)alloc((DD / 2) * 4);
    float* wr2     = (float*)alloc((size_t)(DD / 2) * (DD / 4) * 4);
    float* br2     = (float*)alloc((DD / 4) * 4);
    float* wr3     = (float*)alloc((size_t)(DD / 4) * NC * 4);
    float* br3     = (float*)alloc(NC * 4);

    detect_kernel<<<1, 64, 0, stream>>>(ei, batch, W_emb, flags);

    Params12 P;
    P.p[0]  = { b_emb, b_emb32, DD, DD };
    P.p[1]  = { b_gcn, b_gcn32, LL * DD, LL * DD };
    P.p[2]  = { bn_g,  bng32,   LL * DD, LL * DD };
    P.p[3]  = { bn_b,  bnb32,   LL * DD, LL * DD };
    P.p[4]  = { W_r1,  wr1,     DD * (DD / 2), DD * (DD / 2) };
    P.p[5]  = { b_r1,  br1,     DD / 2, DD / 2 };
    P.p[6]  = { W_r2,  wr2,     (DD / 2) * (DD / 4), (DD / 2) * (DD / 4) };
    P.p[7]  = { b_r2,  br2,     DD / 4, DD / 4 };
    P.p[8]  = { W_r3,  wr3,     (DD / 4) * NC, (DD / 4) * NC };
    P.p[9]  = { b_r3,  br3,     NC, NC };
    P.p[10] = { b_r3,  br3,     0, 0 };
    P.p[11] = { b_r3,  br3,     0, 0 };

    WtDescs5 W;
    W.p[0] = { W_emb, 0,            wt_emb,                DIN, KP_EMB };
    W.p[1] = { W_gcn, 0L * DD * DD, wt_gcn + 0L * DD * DD, DD,  DD };
    W.p[2] = { W_gcn, 1L * DD * DD, wt_gcn + 1L * DD * DD, DD,  DD };
    W.p[3] = { W_gcn, 2L * DD * DD, wt_gcn + 2L * DD * DD, DD,  DD };
    W.p[4] = { W_gcn, 3L * DD * DD, wt_gcn + 3L * DD * DD, DD,  DD };

    mega_conv_kernel<<<C_WT, 256, 0, stream>>>(x, batch, flags, xb, deg, statmulti,
                                               hgsum, b32, P, W);

    edge_emb_kernel<<<B_TOT, 256, 0, stream>>>(ei, flags, src32, dst32, rank, deg,
                                               xb, wt_emb, b_emb32, hb, NN);

    int nb = (NN + 255) / 256;  // 196
    scan1_kernel<<<nb, 256, 0, stream>>>(deg, off, bsum, dinv, NN);
    scan2_kernel<<<1, 256, 0, stream>>>(bsum, boff, off + NN, nb);
    scan3_kernel<<<nb, 256, 0, stream>>>(off, boff, NN);

    scat_mm_kernel<<<S_TOT, 256, 0, stream>>>(src32, dst32, rank, off, src_s,
                                              hb, wt_gcn, dinv, mb, NN);

    int ngemm = (NN + 127) / 128;  // 391
    int nagg = (NN + 4 * NPW - 1) / (4 * NPW);  // 3125 blocks (16 nodes/block)
    for (int l = 0; l < LL; ++l) {
        if (l > 0) {
            gemm_fused_kernel<<<ngemm, 256, 0, stream>>>(
                aggb, hb, statmulti + (size_t)(l - 1) * NCOPY * 256,
                bng32 + (l - 1) * DD, bnb32 + (l - 1) * DD,
                dinv, wt_gcn + (size_t)l * DD * DD, mb, NN);
        }
        agg_kernel<<<nagg, 256, 0, stream>>>(mb, off, src_s, dinv,
                                             b_gcn32 + l * DD, aggb,
                                             statmulti + (size_t)l * NCOPY * 256);
    }

    pool1_kernel<<<512, 256, 0, stream>>>(hb, aggb, statmulti + (size_t)(LL - 1) * NCOPY * 256,
                                          bng32 + (LL - 1) * DD, bnb32 + (LL - 1) * DD,
                                          b32, hgsum, NN);
    readout_kernel<<<GG, DD, 0, stream>>>(hgsum, b32, wr1, br1, wr2, br2, wr3, br3,
                                          flags, d_out, NN);
}

// Round 15
// 439.701 us; speedup vs baseline: 1.8858x; 1.0117x over previous
//
#include <hip/hip_runtime.h>
#include <hip/hip_bf16.h>

// Problem constants (fixed by the reference)
#define NN 50000
#define EE 800000
#define DIN 146
#define DD 128
#define GG 64
#define LL 4
#define NC 10
#define BN_EPS 1e-5f

#define KP_EMB 160    // 146 padded to multiple of 32
#define AST_L  136    // LDS A stride (shorts) for fused gemm
#define NCOPY 64      // stat accumulator copies (contention spreading)
#define NPW 4         // nodes per wave in agg
#define RST 129       // agg LDS group stride (floats)

// mega_conv block ranges: init / repack / batch / params / wt
#define C_INIT   256
#define C_REPACK (C_INIT + 31250)
#define C_BATCH  (C_REPACK + 196)
#define C_PARAMS (C_BATCH + 384)
#define C_WT     (C_PARAMS + 400)

// edge_emb: edge conv (3125) + emb gemm (391)
#define B_EDGE 3125
#define B_TOT  (B_EDGE + 391)
// scat_mm: scatter (3125) + gemm_plain (391)
#define S_SCAT 3125
#define S_TOT  (S_SCAT + 391)

typedef __attribute__((ext_vector_type(8))) short bf16x8;
typedef __attribute__((ext_vector_type(4))) float f32x4;

__device__ __forceinline__ float bf2f(__hip_bfloat16 v) { return __bfloat162float(v); }
__device__ __forceinline__ float loadf(const void* p, long i, int f32) {
    return f32 ? ((const float*)p)[i] : bf2f(((const __hip_bfloat16*)p)[i]);
}
__device__ __forceinline__ unsigned short f2bf_bits(float f) {
    __hip_bfloat16 h = __float2bfloat16(f);
    return *(unsigned short*)&h;
}
__device__ __forceinline__ float bfu2f(unsigned short u) {
    return __uint_as_float((unsigned)u << 16);
}
__device__ __forceinline__ void acc_add8(float* acc, uint4 v) {
    acc[0] += __uint_as_float(v.x << 16);
    acc[1] += __uint_as_float(v.x & 0xffff0000u);
    acc[2] += __uint_as_float(v.y << 16);
    acc[3] += __uint_as_float(v.y & 0xffff0000u);
    acc[4] += __uint_as_float(v.z << 16);
    acc[5] += __uint_as_float(v.z & 0xffff0000u);
    acc[6] += __uint_as_float(v.w << 16);
    acc[7] += __uint_as_float(v.w & 0xffff0000u);
}

// flags[0]=edge_index int64, flags[1]=batch int64, flags[2]=floats are f32
__global__ void detect_kernel(const void* ei, const void* batch, const void* Wemb,
                              int* __restrict__ flags) {
    __shared__ int s_edge_nz, s_batch_nz, s_f32_cnt;
    int t = threadIdx.x;  // 64
    if (t == 0) { s_edge_nz = 0; s_batch_nz = 0; s_f32_cnt = 0; }
    __syncthreads();
    {   const int* w = (const int*)ei;
        long j = ((long)t * ((2L * EE) / 64)) | 1;
        if (w[j] != 0) atomicAdd(&s_edge_nz, 1);
    }
    {   const int* w = (const int*)batch;
        long j = ((long)(NN / 2) + (long)t * ((NN / 2) / 64)) | 1;
        if (j < NN && w[j] != 0) atomicAdd(&s_batch_nz, 1);
    }
    {   const unsigned short* w = (const unsigned short*)Wemb;
        unsigned short v = w[2 * t];
        int ex = (v >> 7) & 0xFF;
        if (v != 0 && ex >= 128) atomicAdd(&s_f32_cnt, 1);
    }
    __syncthreads();
    if (t == 0) {
        flags[0] = (s_edge_nz == 0) ? 1 : 0;
        flags[1] = (s_batch_nz == 0) ? 1 : 0;
        flags[2] = (s_f32_cnt >= 8) ? 1 : 0;
    }
}

struct Param { const void* src; float* dst; int src_n; int dst_n; };
struct Params12 { Param p[12]; };
struct WtDesc { const void* src; long src_off; unsigned short* dst; int K; int Kpad; };
struct WtDescs5 { WtDesc p[5]; };

// merged conversions + zero-init (no atomics; all independent)
__global__ __launch_bounds__(256) void mega_conv_kernel(
    const void* __restrict__ x, const void* __restrict__ batch,
    const int* __restrict__ flags, unsigned short* __restrict__ xb,
    int* __restrict__ deg, float* __restrict__ statmulti, float* __restrict__ hgsum,
    int* __restrict__ b32, Params12 P, WtDescs5 W)
{
    int b = blockIdx.x;
    int t = threadIdx.x;
    if (b < C_INIT) {
        int i = b * 256 + t;
        if (i < NN) deg[i] = 0;
        if (i < LL * NCOPY * 256) statmulti[i] = 0.0f;
        if (i < GG * DD) hgsum[i] = 0.0f;
    } else if (b < C_REPACK) {
        int f32 = flags[2];
        long idx = (long)(b - C_INIT) * 256 + t;  // < 8,000,000 exactly
        int row = (int)(idx / KP_EMB);
        int k = (int)(idx - (long)row * KP_EMB);
        float v = (k < DIN) ? loadf(x, (long)row * DIN + k, f32) : 0.0f;
        xb[idx] = f2bf_bits(v);
    } else if (b < C_BATCH) {
        int i = (b - C_REPACK) * 256 + t;
        if (i < NN) b32[i] = flags[1] ? ((const int*)batch)[2L * i] : ((const int*)batch)[i];
    } else if (b < C_PARAMS) {
        int f32 = flags[2];
        int bb = b - C_BATCH;
        const Param& e = P.p[bb >> 5];
        int idx = (bb & 31) * 256 + t;
        if (idx < e.dst_n)
            e.dst[idx] = (idx < e.src_n) ? loadf(e.src, idx, f32) : 0.0f;
    } else {
        int f32 = flags[2];
        int bb = b - C_PARAMS;
        int y = bb / 80;
        const WtDesc& e = W.p[y];
        int idx = (bb - y * 80) * 256 + t;
        if (idx < 128 * e.Kpad) {
            int n = idx / e.Kpad, k = idx - n * e.Kpad;
            float v = (k < e.K) ? loadf(e.src, e.src_off + (long)k * DD + n, f32) : 0.0f;
            e.dst[idx] = f2bf_bits(v);
        }
    }
}

// ---- MFMA layouts ----
// A frag: m=lane&15, k=quad*8+j   B frag (from W^T): n=lane&15, k=quad*8+j
// C/D:    col=lane&15, row=quad*4+reg

// merged: edge conv+deg+rank (latency-bound atomics) || emb MFMA gemm (hb bf16)
__global__ __launch_bounds__(256) void edge_emb_kernel(
    const void* __restrict__ ei, const int* __restrict__ flags,
    int* __restrict__ src32, int* __restrict__ dst32,
    int* __restrict__ rank, int* __restrict__ deg,
    const unsigned short* __restrict__ Ab,   // xb [n][160] bf16
    const unsigned short* __restrict__ Wt,   // [128][160] bf16 transposed
    const float* __restrict__ bias,
    unsigned short* __restrict__ hb, int n)
{
    int t = threadIdx.x;
    if (blockIdx.x < B_EDGE) {
        int e = blockIdx.x * 256 + t;  // < 800000 exactly
        const int* w = (const int*)ei;
        int s, d;
        if (flags[0]) { s = w[2L * e]; d = w[2L * (EE + e)]; }
        else          { s = w[e];      d = w[EE + e]; }
        src32[e] = s; dst32[e] = d;
        int r = 0;
        if ((unsigned)d < (unsigned)NN) r = atomicAdd(&deg[d], 1);
        rank[e] = r;
        return;
    }
    int r0 = (blockIdx.x - B_EDGE) * 128;
    int lane = t & 63, w = t >> 6;
    int m = lane & 15, quad = lane >> 4;
    int rbase = r0 + w * 32;
    bf16x8 a[2][5];
    #pragma unroll
    for (int rt = 0; rt < 2; ++rt)
        #pragma unroll
        for (int c = 0; c < 5; ++c) {
            int rr = rbase + rt * 16 + m; if (rr > n - 1) rr = n - 1;
            a[rt][c] = *(const bf16x8*)(Ab + (long)rr * KP_EMB + c * 32 + quad * 8);
        }
    f32x4 acc[2][8];
    #pragma unroll
    for (int t8 = 0; t8 < 8; ++t8) {
        float bv = bias[t8 * 16 + m];
        f32x4 ai = {bv, bv, bv, bv};
        acc[0][t8] = ai; acc[1][t8] = ai;
    }
    #pragma unroll
    for (int t8 = 0; t8 < 8; ++t8) {
        #pragma unroll
        for (int c = 0; c < 5; ++c) {
            bf16x8 b = *(const bf16x8*)(Wt + (long)(t8 * 16 + m) * KP_EMB + c * 32 + quad * 8);
            acc[0][t8] = __builtin_amdgcn_mfma_f32_16x16x32_bf16(a[0][c], b, acc[0][t8], 0, 0, 0);
            acc[1][t8] = __builtin_amdgcn_mfma_f32_16x16x32_bf16(a[1][c], b, acc[1][t8], 0, 0, 0);
        }
    }
    #pragma unroll
    for (int rt = 0; rt < 2; ++rt)
        #pragma unroll
        for (int t8 = 0; t8 < 8; ++t8)
            #pragma unroll
            for (int rg = 0; rg < 4; ++rg) {
                int row = rbase + rt * 16 + quad * 4 + rg;
                int col = t8 * 16 + m;
                if (row < n) hb[(long)row * DD + col] = f2bf_bits(acc[rt][t8][rg]);
            }
}

// ---- 2-phase scan: off holds within-block prefixes; consumers add boff[i>>8] ----
__global__ void scan1_kernel(const int* __restrict__ cnt, int* __restrict__ off,
                             int* __restrict__ bsum, float* __restrict__ dinv, int n) {
    int t = threadIdx.x;
    int i = blockIdx.x * 256 + t;
    int v = (i < n) ? cnt[i] : 0;
    if (i < n) dinv[i] = rsqrtf((float)(v + 1));  // +1 self-loop
    int lane = t & 63, w = t >> 6;
    int x = v;
    #pragma unroll
    for (int s = 1; s < 64; s <<= 1) {
        int y = __shfl_up(x, s, 64);
        if (lane >= s) x += y;
    }
    __shared__ int wsum[4];
    if (lane == 63) wsum[w] = x;
    __syncthreads();
    if (t == 0) {
        int a = 0;
        #pragma unroll
        for (int k = 0; k < 4; ++k) { int tmp = wsum[k]; wsum[k] = a; a += tmp; }
        bsum[blockIdx.x] = a;
    }
    __syncthreads();
    int excl = x - v + wsum[w];
    if (i < n) off[i] = excl;
}

// boff[b] = global prefix of block b; off[NN] set so off[NN]+boff[nb-1] == total
__global__ void scan2_kernel(int* __restrict__ bsum, int* __restrict__ boff,
                             int* __restrict__ off_last, int nb) {
    int t = threadIdx.x;  // 256
    int v = (t < nb) ? bsum[t] : 0;
    int lane = t & 63, w = t >> 6;
    int x = v;
    #pragma unroll
    for (int s = 1; s < 64; s <<= 1) {
        int y = __shfl_up(x, s, 64);
        if (lane >= s) x += y;
    }
    __shared__ int wsum[4];
    if (lane == 63) wsum[w] = x;
    __syncthreads();
    __shared__ int total_s;
    if (t == 0) {
        int a = 0;
        #pragma unroll
        for (int k = 0; k < 4; ++k) { int tmp = wsum[k]; wsum[k] = a; a += tmp; }
        total_s = a;
    }
    __syncthreads();
    int bval = x - v + wsum[w];
    if (t < nb) boff[t] = bval;
    if (t == nb - 1) *off_last = total_s - bval;
}

// merged: CSR scatter (boff-fused, latency-bound) || layer-0 gemm_plain (MFMA)
__global__ __launch_bounds__(256) void scat_mm_kernel(
    const int* __restrict__ src, const int* __restrict__ dst,
    const int* __restrict__ rank, const int* __restrict__ off,
    const int* __restrict__ boff, int* __restrict__ src_s,
    const unsigned short* __restrict__ Ab,   // hb
    const unsigned short* __restrict__ Wt,   // wt_gcn layer 0
    const float* __restrict__ dinv,
    unsigned short* __restrict__ Mb, int n)
{
    int t = threadIdx.x;
    if (blockIdx.x < S_SCAT) {
        int e = blockIdx.x * 256 + t;  // < 800000 exactly
        int s = src[e], d = dst[e];
        if ((unsigned)s >= (unsigned)NN || (unsigned)d >= (unsigned)NN) return;
        src_s[off[d] + boff[d >> 8] + rank[e]] = s;
        return;
    }
    int r0 = (blockIdx.x - S_SCAT) * 128;
    int lane = t & 63, w = t >> 6;
    int m = lane & 15, quad = lane >> 4;
    int rbase = r0 + w * 32;
    bf16x8 a[2][4];
    #pragma unroll
    for (int rt = 0; rt < 2; ++rt)
        #pragma unroll
        for (int c = 0; c < 4; ++c) {
            int rr = rbase + rt * 16 + m; if (rr > n - 1) rr = n - 1;
            a[rt][c] = *(const bf16x8*)(Ab + (long)rr * DD + c * 32 + quad * 8);
        }
    float dv[2][4];
    #pragma unroll
    for (int rt = 0; rt < 2; ++rt)
        #pragma unroll
        for (int rg = 0; rg < 4; ++rg) {
            int row = rbase + rt * 16 + quad * 4 + rg; if (row > n - 1) row = n - 1;
            dv[rt][rg] = dinv[row];
        }
    f32x4 acc[2][8];
    #pragma unroll
    for (int t8 = 0; t8 < 8; ++t8) {
        f32x4 z = {0.f, 0.f, 0.f, 0.f};
        acc[0][t8] = z; acc[1][t8] = z;
    }
    #pragma unroll
    for (int t8 = 0; t8 < 8; ++t8) {
        #pragma unroll
        for (int c = 0; c < 4; ++c) {
            bf16x8 b = *(const bf16x8*)(Wt + (long)(t8 * 16 + m) * DD + c * 32 + quad * 8);
            acc[0][t8] = __builtin_amdgcn_mfma_f32_16x16x32_bf16(a[0][c], b, acc[0][t8], 0, 0, 0);
            acc[1][t8] = __builtin_amdgcn_mfma_f32_16x16x32_bf16(a[1][c], b, acc[1][t8], 0, 0, 0);
        }
    }
    #pragma unroll
    for (int rt = 0; rt < 2; ++rt)
        #pragma unroll
        for (int t8 = 0; t8 < 8; ++t8)
            #pragma unroll
            for (int rg = 0; rg < 4; ++rg) {
                int row = rbase + rt * 16 + quad * 4 + rg;
                int col = t8 * 16 + m;
                if (row < n) Mb[(long)row * DD + col] = f2bf_bits(dv[rt][rg] * acc[rt][t8][rg]);
            }
}

// fused: inline stats-finalize + hb += relu(bn(aggb)) (bf16 in-place) + MFMA
__global__ __launch_bounds__(256) void gemm_fused_kernel(
    const unsigned short* __restrict__ aggb, unsigned short* __restrict__ hb,
    const float* __restrict__ statmulti, const float* __restrict__ gamma,
    const float* __restrict__ beta, const float* __restrict__ dinv,
    const unsigned short* __restrict__ Wt, unsigned short* __restrict__ Mb, int n)
{
    __shared__ unsigned short As[128 * AST_L];
    __shared__ float bnsh[256];
    int t = threadIdx.x;
    int r0 = blockIdx.x * 128;
    {
        float s = 0.0f;
        #pragma unroll 8
        for (int k = 0; k < NCOPY; ++k) s += statmulti[k * 256 + t];
        bnsh[t] = s;
    }
    __syncthreads();
    {
        int c4 = (t & 31) * 4, rsub = t >> 5;  // 8 row substreams
        float inv_n = 1.0f / (float)n;
        float4 sm = *(const float4*)&bnsh[c4];
        float4 sq = *(const float4*)&bnsh[128 + c4];
        float4 ga = *(const float4*)&gamma[c4];
        float4 be = *(const float4*)&beta[c4];
        float4 mu, rs;
        mu.x = sm.x * inv_n; mu.y = sm.y * inv_n; mu.z = sm.z * inv_n; mu.w = sm.w * inv_n;
        rs.x = rsqrtf(sq.x * inv_n - mu.x * mu.x + BN_EPS) * ga.x;
        rs.y = rsqrtf(sq.y * inv_n - mu.y * mu.y + BN_EPS) * ga.y;
        rs.z = rsqrtf(sq.z * inv_n - mu.z * mu.z + BN_EPS) * ga.z;
        rs.w = rsqrtf(sq.w * inv_n - mu.w * mu.w + BN_EPS) * ga.w;
        #pragma unroll 4
        for (int i = 0; i < 16; ++i) {
            int row = i * 8 + rsub;
            int r = r0 + row;
            unsigned short o0 = 0, o1 = 0, o2 = 0, o3 = 0;
            if (r < n) {
                long g = (long)r * DD + c4;
                ushort4 au = *(const ushort4*)&aggb[g];
                ushort4 hu = *(const ushort4*)&hb[g];
                float h0 = bfu2f(hu.x) + fmaxf((bfu2f(au.x) - mu.x) * rs.x + be.x, 0.0f);
                float h1 = bfu2f(hu.y) + fmaxf((bfu2f(au.y) - mu.y) * rs.y + be.y, 0.0f);
                float h2 = bfu2f(hu.z) + fmaxf((bfu2f(au.z) - mu.z) * rs.z + be.z, 0.0f);
                float h3 = bfu2f(hu.w) + fmaxf((bfu2f(au.w) - mu.w) * rs.w + be.w, 0.0f);
                o0 = f2bf_bits(h0); o1 = f2bf_bits(h1);
                o2 = f2bf_bits(h2); o3 = f2bf_bits(h3);
                ushort4 ho; ho.x = o0; ho.y = o1; ho.z = o2; ho.w = o3;
                *(ushort4*)&hb[g] = ho;
            }
            unsigned short* dst = &As[row * AST_L + c4];
            dst[0] = o0; dst[1] = o1; dst[2] = o2; dst[3] = o3;
        }
    }
    __syncthreads();
    int lane = t & 63, w = t >> 6;
    int m = lane & 15, quad = lane >> 4;
    int rl = w * 32;
    int rbase = r0 + rl;
    bf16x8 a[2][4];
    #pragma unroll
    for (int rt = 0; rt < 2; ++rt)
        #pragma unroll
        for (int c = 0; c < 4; ++c)
            a[rt][c] = *(const bf16x8*)(As + (rl + rt * 16 + m) * AST_L + c * 32 + quad * 8);
    float dv[2][4];
    #pragma unroll
    for (int rt = 0; rt < 2; ++rt)
        #pragma unroll
        for (int rg = 0; rg < 4; ++rg) {
            int row = rbase + rt * 16 + quad * 4 + rg; if (row > n - 1) row = n - 1;
            dv[rt][rg] = dinv[row];
        }
    f32x4 acc[2][8];
    #pragma unroll
    for (int t8 = 0; t8 < 8; ++t8) {
        f32x4 z = {0.f, 0.f, 0.f, 0.f};
        acc[0][t8] = z; acc[1][t8] = z;
    }
    #pragma unroll
    for (int t8 = 0; t8 < 8; ++t8) {
        #pragma unroll
        for (int c = 0; c < 4; ++c) {
            bf16x8 b = *(const bf16x8*)(Wt + (long)(t8 * 16 + m) * DD + c * 32 + quad * 8);
            acc[0][t8] = __builtin_amdgcn_mfma_f32_16x16x32_bf16(a[0][c], b, acc[0][t8], 0, 0, 0);
            acc[1][t8] = __builtin_amdgcn_mfma_f32_16x16x32_bf16(a[1][c], b, acc[1][t8], 0, 0, 0);
        }
    }
    #pragma unroll
    for (int rt = 0; rt < 2; ++rt)
        #pragma unroll
        for (int t8 = 0; t8 < 8; ++t8)
            #pragma unroll
            for (int rg = 0; rg < 4; ++rg) {
                int row = rbase + rt * 16 + quad * 4 + rg;
                int col = t8 * 16 + m;
                if (row < n) Mb[(long)row * DD + col] = f2bf_bits(dv[rt][rg] * acc[rt][t8][rg]);
            }
}

// aggb[i] = bf16( dinv[i] * (mbS[i] + sum_e mbS[src_s[e]]) + bias ), fused stats.
// CSR bounds via off[i]+boff[i>>8]. 16-edge unroll: 4 dwordx4 gathers in flight.
__global__ __launch_bounds__(256) void agg_kernel(
    const unsigned short* __restrict__ mb, const int* __restrict__ off,
    const int* __restrict__ boff, const int* __restrict__ src_s,
    const float* __restrict__ dinv, const float* __restrict__ bias,
    unsigned short* __restrict__ aggb, float* __restrict__ statacc)
{
    __shared__ float sred[4][4 * RST];
    __shared__ float2 ssum[4][64], ssq[4][64];
    int t = threadIdx.x;
    int wv = t >> 6, lane = t & 63;
    int grp = lane >> 4, sl = lane & 15;
    float* red = sred[wv];
    float2 bi = ((const float2*)bias)[lane];
    float2 sAcc = {0.0f, 0.0f}, qAcc = {0.0f, 0.0f};
    int i0 = (blockIdx.x * 4 + wv) * NPW;
    #pragma unroll 1
    for (int ni = 0; ni < NPW; ++ni) {
        int i = i0 + ni;
        if (i >= NN) break;
        float acc[8];
        #pragma unroll
        for (int k = 0; k < 8; ++k) acc[k] = 0.0f;
        if (grp == 0) {
            uint4 v = *(const uint4*)(mb + (long)i * DD + sl * 8);
            acc_add8(acc, v);
        }
        int e  = off[i] + boff[i >> 8];
        int e1 = off[i + 1] + boff[(i + 1) >> 8];
        for (; e + 16 <= e1; e += 16) {
            int j0 = src_s[e + grp];
            int j1 = src_s[e + 4 + grp];
            int j2 = src_s[e + 8 + grp];
            int j3 = src_s[e + 12 + grp];
            uint4 v0 = *(const uint4*)(mb + (long)j0 * DD + sl * 8);
            uint4 v1 = *(const uint4*)(mb + (long)j1 * DD + sl * 8);
            uint4 v2 = *(const uint4*)(mb + (long)j2 * DD + sl * 8);
            uint4 v3 = *(const uint4*)(mb + (long)j3 * DD + sl * 8);
            acc_add8(acc, v0);
            acc_add8(acc, v1);
            acc_add8(acc, v2);
            acc_add8(acc, v3);
        }
        for (; e + 8 <= e1; e += 8) {
            int ja = src_s[e + grp];
            int jb = src_s[e + 4 + grp];
            uint4 va = *(const uint4*)(mb + (long)ja * DD + sl * 8);
            uint4 vb = *(const uint4*)(mb + (long)jb * DD + sl * 8);
            acc_add8(acc, va);
            acc_add8(acc, vb);
        }
        for (; e + 4 <= e1; e += 4) {
            int j = src_s[e + grp];
            uint4 v = *(const uint4*)(mb + (long)j * DD + sl * 8);
            acc_add8(acc, v);
        }
        if (e + grp < e1) {
            int j = src_s[e + grp];
            uint4 v = *(const uint4*)(mb + (long)j * DD + sl * 8);
            acc_add8(acc, v);
        }
        #pragma unroll
        for (int k = 0; k < 8; ++k) red[grp * RST + sl * 8 + k] = acc[k];
        asm volatile("" ::: "memory");
        float c0 = 0.0f, c1 = 0.0f;
        #pragma unroll
        for (int g = 0; g < 4; ++g) {
            c0 += red[g * RST + 2 * lane];
            c1 += red[g * RST + 2 * lane + 1];
        }
        asm volatile("" ::: "memory");
        float di = dinv[i];
        float o0 = di * c0 + bi.x;
        float o1 = di * c1 + bi.y;
        unsigned packed = ((unsigned)f2bf_bits(o1) << 16) | f2bf_bits(o0);
        ((unsigned*)aggb)[(long)i * 64 + lane] = packed;
        sAcc.x += o0; sAcc.y += o1;
        qAcc.x += o0 * o0; qAcc.y += o1 * o1;
    }
    ssum[wv][lane] = sAcc; ssq[wv][lane] = qAcc;
    __syncthreads();
    if (wv == 0) {
        float2 s0 = ssum[0][lane], s1 = ssum[1][lane], s2 = ssum[2][lane], s3 = ssum[3][lane];
        float2 q0 = ssq[0][lane], q1 = ssq[1][lane], q2 = ssq[2][lane], q3 = ssq[3][lane];
        float sx = s0.x + s1.x + s2.x + s3.x;
        float sy = s0.y + s1.y + s2.y + s3.y;
        float qx = q0.x + q1.x + q2.x + q3.x;
        float qy = q0.y + q1.y + q2.y + q3.y;
        float* copy = statacc + (blockIdx.x & (NCOPY - 1)) * 256;
        atomicAdd(&copy[2 * lane], sx);
        atomicAdd(&copy[2 * lane + 1], sy);
        atomicAdd(&copy[128 + 2 * lane], qx);
        atomicAdd(&copy[128 + 2 * lane + 1], qy);
    }
}

// pooling with inline stats-finalize + fused final BN+relu+residual (bf16 inputs)
__global__ void pool1_kernel(const unsigned short* __restrict__ hb,
                             const unsigned short* __restrict__ aggb,
                             const float* __restrict__ statmulti,
                             const float* __restrict__ gamma, const float* __restrict__ beta,
                             const int* __restrict__ b32, float* __restrict__ hgsum, int n) {
    __shared__ float bnsh[256];
    int t = threadIdx.x;
    {
        float s = 0.0f;
        #pragma unroll 8
        for (int k = 0; k < NCOPY; ++k) s += statmulti[k * 256 + t];
        bnsh[t] = s;
    }
    __syncthreads();
    int c4 = (t & 31) * 4, rsub = t >> 5;
    float inv_n = 1.0f / (float)n;
    float4 sm = *(const float4*)&bnsh[c4];
    float4 sq = *(const float4*)&bnsh[128 + c4];
    float4 ga = *(const float4*)&gamma[c4];
    float4 be = *(const float4*)&beta[c4];
    float4 mu, rs;
    mu.x = sm.x * inv_n; mu.y = sm.y * inv_n; mu.z = sm.z * inv_n; mu.w = sm.w * inv_n;
    rs.x = rsqrtf(sq.x * inv_n - mu.x * mu.x + BN_EPS) * ga.x;
    rs.y = rsqrtf(sq.y * inv_n - mu.y * mu.y + BN_EPS) * ga.y;
    rs.z = rsqrtf(sq.z * inv_n - mu.z * mu.z + BN_EPS) * ga.z;
    rs.w = rsqrtf(sq.w * inv_n - mu.w * mu.w + BN_EPS) * ga.w;
    int rows_pb = (n + gridDim.x - 1) / gridDim.x;
    int r0 = blockIdx.x * rows_pb;
    int r1 = min(n, r0 + rows_pb);
    float4 acc = {0, 0, 0, 0};
    int gcur = -1;
    for (int r = r0 + rsub; r < r1; r += 8) {
        int g = b32[r];
        if (g != gcur) {
            if (gcur >= 0) {
                atomicAdd(&hgsum[gcur * DD + c4 + 0], acc.x);
                atomicAdd(&hgsum[gcur * DD + c4 + 1], acc.y);
                atomicAdd(&hgsum[gcur * DD + c4 + 2], acc.z);
                atomicAdd(&hgsum[gcur * DD + c4 + 3], acc.w);
            }
            acc.x = acc.y = acc.z = acc.w = 0.0f;
            gcur = ((unsigned)g < (unsigned)GG) ? g : -1;
        }
        if (gcur >= 0) {
            long ix = (long)r * DD + c4;
            ushort4 au = *(const ushort4*)&aggb[ix];
            ushort4 hu = *(const ushort4*)&hb[ix];
            acc.x += bfu2f(hu.x) + fmaxf((bfu2f(au.x) - mu.x) * rs.x + be.x, 0.0f);
            acc.y += bfu2f(hu.y) + fmaxf((bfu2f(au.y) - mu.y) * rs.y + be.y, 0.0f);
            acc.z += bfu2f(hu.z) + fmaxf((bfu2f(au.z) - mu.z) * rs.z + be.z, 0.0f);
            acc.w += bfu2f(hu.w) + fmaxf((bfu2f(au.w) - mu.w) * rs.w + be.w, 0.0f);
        }
    }
    if (gcur >= 0) {
        atomicAdd(&hgsum[gcur * DD + c4 + 0], acc.x);
        atomicAdd(&hgsum[gcur * DD + c4 + 1], acc.y);
        atomicAdd(&hgsum[gcur * DD + c4 + 2], acc.z);
        atomicAdd(&hgsum[gcur * DD + c4 + 3], acc.w);
    }
}

__device__ int lower_bound_i(const int* __restrict__ a, int n, int v) {
    int lo = 0, hi = n;
    while (lo < hi) {
        int mid = (lo + hi) >> 1;
        if (a[mid] < v) lo = mid + 1; else hi = mid;
    }
    return lo;
}

// readout with fused mean-pool finalize
__global__ void readout_kernel(const float* __restrict__ hgsum, const int* __restrict__ b32,
                               const float* __restrict__ W1, const float* __restrict__ b1,
                               const float* __restrict__ W2, const float* __restrict__ b2,
                               const float* __restrict__ W3, const float* __restrict__ b3,
                               const int* __restrict__ flags, void* __restrict__ out, int n) {
    int f32 = flags[2];
    int g = blockIdx.x;
    int t = threadIdx.x;
    __shared__ float hgs[DD];
    __shared__ float z1[DD / 2];
    __shared__ float z2[DD / 4];
    int lo = lower_bound_i(b32, n, g);
    int hi = lower_bound_i(b32, n, g + 1);
    float invc = 1.0f / fmaxf((float)(hi - lo), 1.0f);
    hgs[t] = hgsum[g * DD + t] * invc;
    __syncthreads();
    if (t < DD / 2) {
        float acc = b1[t];
        #pragma unroll 8
        for (int k = 0; k < DD; ++k) acc = fmaf(hgs[k], W1[k * (DD / 2) + t], acc);
        z1[t] = fmaxf(acc, 0.0f);
    }
    __syncthreads();
    if (t < DD / 4) {
        float acc = b2[t];
        #pragma unroll 8
        for (int k = 0; k < DD / 2; ++k) acc = fmaf(z1[k], W2[k * (DD / 4) + t], acc);
        z2[t] = fmaxf(acc, 0.0f);
    }
    __syncthreads();
    if (t < NC) {
        float acc = b3[t];
        #pragma unroll 8
        for (int k = 0; k < DD / 4; ++k) acc = fmaf(z2[k], W3[k * NC + t], acc);
        if (f32) ((float*)out)[g * NC + t] = acc;
        else     ((__hip_bfloat16*)out)[g * NC + t] = __float2bfloat16(acc);
    }
}

extern "C" void kernel_launch(void* const* d_in, const int* in_sizes, int n_in,
                              void* d_out, int out_size, void* d_ws, size_t ws_size,
                              hipStream_t stream) {
    const void* x      = d_in[0];
    const void* ei     = d_in[1];
    const void* batch  = d_in[2];
    const void* W_emb  = d_in[3];
    const void* b_emb  = d_in[4];
    const void* W_gcn  = d_in[5];
    const void* b_gcn  = d_in[6];
    const void* bn_g   = d_in[7];
    const void* bn_b   = d_in[8];
    const void* W_r1   = d_in[9];
    const void* b_r1   = d_in[10];
    const void* W_r2   = d_in[11];
    const void* b_r2   = d_in[12];
    const void* W_r3   = d_in[13];
    const void* b_r3   = d_in[14];

    char* p = (char*)d_ws;
    auto alloc = [&](size_t bytes) -> void* {
        void* r = (void*)p;
        p += (bytes + 255) & ~(size_t)255;
        return r;
    };
    int*   flags  = (int*)alloc(64 * 4);
    int*   deg    = (int*)alloc((size_t)NN * 4);
    float* statmulti = (float*)alloc((size_t)LL * NCOPY * 256 * 4);
    float* hgsum  = (float*)alloc((size_t)GG * DD * 4);
    int*   off    = (int*)alloc((size_t)(NN + 1) * 4);
    float* dinv   = (float*)alloc((size_t)NN * 4);
    int*   src32  = (int*)alloc((size_t)EE * 4);
    int*   dst32  = (int*)alloc((size_t)EE * 4);
    int*   rank   = (int*)alloc((size_t)EE * 4);
    int*   b32    = (int*)alloc((size_t)NN * 4);
    int*   src_s  = (int*)alloc((size_t)EE * 4);
    int*   bsum   = (int*)alloc(256 * 4);
    int*   boff   = (int*)alloc(256 * 4);
    unsigned short* hb = (unsigned short*)alloc((size_t)NN * DD * 2);
    unsigned short* mb = (unsigned short*)alloc((size_t)NN * DD * 2);
    unsigned short* aggb = (unsigned short*)alloc((size_t)NN * DD * 2);
    unsigned short* xb = (unsigned short*)alloc((size_t)NN * KP_EMB * 2);
    // canonical params
    unsigned short* wt_emb = (unsigned short*)alloc((size_t)DD * KP_EMB * 2);
    unsigned short* wt_gcn = (unsigned short*)alloc((size_t)LL * DD * DD * 2);
    float* b_emb32 = (float*)alloc(DD * 4);
    float* b_gcn32 = (float*)alloc((size_t)LL * DD * 4);
    float* bng32   = (float*)alloc((size_t)LL * DD * 4);
    float* bnb32   = (float*)alloc((size_t)LL * DD * 4);
    float* wr1     = (float*)alloc((size_t)DD * (DD / 2) * 4);
    float* br1     = (float*)alloc((DD / 2) * 4);
    float* wr2     = (float*)alloc((size_t)(DD / 2) * (DD / 4) * 4);
    float* br2     = (float*)alloc((DD / 4) * 4);
    float* wr3     = (float*)alloc((size_t)(DD / 4) * NC * 4);
    float* br3     = (float*)alloc(NC * 4);

    detect_kernel<<<1, 64, 0, stream>>>(ei, batch, W_emb, flags);

    Params12 P;
    P.p[0]  = { b_emb, b_emb32, DD, DD };
    P.p[1]  = { b_gcn, b_gcn32, LL * DD, LL * DD };
    P.p[2]  = { bn_g,  bng32,   LL * DD, LL * DD };
    P.p[3]  = { bn_b,  bnb32,   LL * DD, LL * DD };
    P.p[4]  = { W_r1,  wr1,     DD * (DD / 2), DD * (DD / 2) };
    P.p[5]  = { b_r1,  br1,     DD / 2, DD / 2 };
    P.p[6]  = { W_r2,  wr2,     (DD / 2) * (DD / 4), (DD / 2) * (DD / 4) };
    P.p[7]  = { b_r2,  br2,     DD / 4, DD / 4 };
    P.p[8]  = { W_r3,  wr3,     (DD / 4) * NC, (DD / 4) * NC };
    P.p[9]  = { b_r3,  br3,     NC, NC };
    P.p[10] = { b_r3,  br3,     0, 0 };
    P.p[11] = { b_r3,  br3,     0, 0 };

    WtDescs5 W;
    W.p[0] = { W_emb, 0,            wt_emb,                DIN, KP_EMB };
    W.p[1] = { W_gcn, 0L * DD * DD, wt_gcn + 0L * DD * DD, DD,  DD };
    W.p[2] = { W_gcn, 1L * DD * DD, wt_gcn + 1L * DD * DD, DD,  DD };
    W.p[3] = { W_gcn, 2L * DD * DD, wt_gcn + 2L * DD * DD, DD,  DD };
    W.p[4] = { W_gcn, 3L * DD * DD, wt_gcn + 3L * DD * DD, DD,  DD };

    mega_conv_kernel<<<C_WT, 256, 0, stream>>>(x, batch, flags, xb, deg, statmulti,
                                               hgsum, b32, P, W);

    edge_emb_kernel<<<B_TOT, 256, 0, stream>>>(ei, flags, src32, dst32, rank, deg,
                                               xb, wt_emb, b_emb32, hb, NN);

    int nb = (NN + 255) / 256;  // 196
    scan1_kernel<<<nb, 256, 0, stream>>>(deg, off, bsum, dinv, NN);
    scan2_kernel<<<1, 256, 0, stream>>>(bsum, boff, off + NN, nb);

    scat_mm_kernel<<<S_TOT, 256, 0, stream>>>(src32, dst32, rank, off, boff, src_s,
                                              hb, wt_gcn, dinv, mb, NN);

    int ngemm = (NN + 127) / 128;  // 391
    int nagg = (NN + 4 * NPW - 1) / (4 * NPW);  // 3125 blocks (16 nodes/block)
    for (int l = 0; l < LL; ++l) {
        if (l > 0) {
            gemm_fused_kernel<<<ngemm, 256, 0, stream>>>(
                aggb, hb, statmulti + (size_t)(l - 1) * NCOPY * 256,
                bng32 + (l - 1) * DD, bnb32 + (l - 1) * DD,
                dinv, wt_gcn + (size_t)l * DD * DD, mb, NN);
        }
        agg_kernel<<<nagg, 256, 0, stream>>>(mb, off, boff, src_s, dinv,
                                             b_gcn32 + l * DD, aggb,
                                             statmulti + (size_t)l * NCOPY * 256);
    }

    pool1_kernel<<<512, 256, 0, stream>>>(hb, aggb, statmulti + (size_t)(LL - 1) * NCOPY * 256,
                                          bng32 + (LL - 1) * DD, bnb32 + (LL - 1) * DD,
                                          b32, hgsum, NN);
    readout_kernel<<<GG, DD, 0, stream>>>(hgsum, b32, wr1, br1, wr2, br2, wr3, br3,
                                          flags, d_out, NN);
}